// Round 1
// baseline (8148.461 us; speedup 1.0000x reference)
//
#include <hip/hip_runtime.h>
#include <hip/hip_bf16.h>

__constant__ float c_mean[3] = {0.485f, 0.456f, 0.406f};
__constant__ float c_istd[3] = {1.0f/0.229f, 1.0f/0.224f, 1.0f/0.225f};

typedef __attribute__((ext_vector_type(8))) short short8;
typedef __attribute__((ext_vector_type(4))) float floatv4;

// ---------------- direct 3x3 conv, stride 1, pad 1, fused bias+relu ----------------
// block = 256 threads; tile = 64(w) x 32(h) x 8 oc; thread = 8x * 1y * 8oc
template<bool NORM>
__global__ __launch_bounds__(256) void conv3x3_k(
    const float* __restrict__ in, const float* __restrict__ wt,
    const float* __restrict__ bias, float* __restrict__ out,
    int IC, int OC, int H, int W,
    int ic_stride, int ic_off, int oc_stride, int oc_off)
{
  __shared__ float tile[34][72];
  __shared__ float wlds[9][8];
  const int tid = threadIdx.x;
  const int xg = tid & 7;
  const int yy = tid >> 3;
  const int oct = OC >> 3;
  const int ocb = blockIdx.z % oct;
  const int b   = blockIdx.z / oct;
  const int oc0 = ocb * 8;
  const int x0 = blockIdx.x * 64;
  const int y0 = blockIdx.y * 32;
  const int ox = x0 + xg * 8;
  const int oy = y0 + yy;

  float acc[8][8];
#pragma unroll
  for (int i = 0; i < 8; ++i)
#pragma unroll
    for (int o = 0; o < 8; ++o) acc[i][o] = 0.f;

  for (int ic = 0; ic < IC; ++ic) {
    __syncthreads();
    const float* inp = in + ((size_t)(b * ic_stride + ic_off + ic) * H) * W;
    for (int idx = tid; idx < 34 * 66; idx += 256) {
      int r = idx / 66;
      int c = idx - r * 66;
      int gy = y0 - 1 + r, gx = x0 - 1 + c;
      float v = 0.f;
      if (gy >= 0 && gy < H && gx >= 0 && gx < W) {
        v = inp[gy * W + gx];
        if (NORM) v = (v - c_mean[ic]) * c_istd[ic];
      }
      tile[r][c] = v;
    }
    if (tid < 72) {
      int o = tid / 9, k = tid - o * 9;
      wlds[k][o] = wt[((size_t)(oc0 + o) * IC + ic) * 9 + k];
    }
    __syncthreads();

    float rows[3][10];
#pragma unroll
    for (int dy = 0; dy < 3; ++dy) {
      const float* rp = &tile[yy + dy][xg * 8];
#pragma unroll
      for (int j = 0; j < 10; ++j) rows[dy][j] = rp[j];
    }
#pragma unroll
    for (int dy = 0; dy < 3; ++dy)
#pragma unroll
      for (int dx = 0; dx < 3; ++dx) {
        float wv[8];
#pragma unroll
        for (int o = 0; o < 8; ++o) wv[o] = wlds[dy * 3 + dx][o];
#pragma unroll
        for (int i = 0; i < 8; ++i) {
          float v = rows[dy][dx + i];
#pragma unroll
          for (int o = 0; o < 8; ++o) acc[i][o] = fmaf(v, wv[o], acc[i][o]);
        }
      }
  }
#pragma unroll
  for (int o = 0; o < 8; ++o) {
    float bv = bias[oc0 + o];
    float* op = out + ((size_t)(b * oc_stride + oc_off + oc0 + o) * H + oy) * W + ox;
#pragma unroll
    for (int i = 0; i < 8; ++i) op[i] = fmaxf(acc[i][o] + bv, 0.f);
  }
}

// ---------------- 2x2 maxpool stride 2 ----------------
__global__ __launch_bounds__(256) void maxpool2_k(const float* __restrict__ in,
                                                  float* __restrict__ out,
                                                  int CT, int H, int W)
{
  int oH = H >> 1, oW = W >> 1, oWq = oW >> 2;
  int total = CT * oH * oWq;
  int idx = blockIdx.x * 256 + threadIdx.x;
  if (idx >= total) return;
  int xq = idx % oWq;
  int t2 = idx / oWq;
  int oy = t2 % oH;
  int c  = t2 / oH;
  const float* ip = in + ((size_t)c * H + 2 * oy) * W + xq * 8;
  float4 a0 = *(const float4*)ip;
  float4 a1 = *(const float4*)(ip + 4);
  float4 b0 = *(const float4*)(ip + W);
  float4 b1 = *(const float4*)(ip + W + 4);
  float4 o;
  o.x = fmaxf(fmaxf(a0.x, a0.y), fmaxf(b0.x, b0.y));
  o.y = fmaxf(fmaxf(a0.z, a0.w), fmaxf(b0.z, b0.w));
  o.z = fmaxf(fmaxf(a1.x, a1.y), fmaxf(b1.x, b1.y));
  o.w = fmaxf(fmaxf(a1.z, a1.w), fmaxf(b1.z, b1.w));
  *(float4*)(out + ((size_t)c * oH + oy) * oW + xq * 4) = o;
}

// ---------------- per-location inverse norms: invn[b,n] = 1/(||feat[b,:,n]||+1e-8) ----------------
__global__ __launch_bounds__(256) void norms_k(const float* __restrict__ cat,
                                               float* __restrict__ invn)
{
  int blk = blockIdx.x;          // B*64 blocks; 64 n per block
  int b = blk >> 6;
  int n0 = (blk & 63) << 6;
  int tid = threadIdx.x;
  int nl = tid & 63;
  int co = tid >> 6;
  const float* p = cat + (size_t)b * 768 * 4096 + n0 + nl;
  float ssq = 0.f;
  for (int c = co; c < 768; c += 4) {
    float v = p[(size_t)c * 4096];
    ssq = fmaf(v, v, ssq);
  }
  __shared__ float red[256];
  red[tid] = ssq;
  __syncthreads();
  if (tid < 128) red[tid] += red[tid + 128];
  __syncthreads();
  if (tid < 64) {
    float s = red[tid] + red[tid + 64];
    invn[(size_t)b * 4096 + n0 + tid] = 1.0f / (sqrtf(s) + 1e-8f);
  }
}

// ---------------- transpose [b][768][4096] -> [b][4096][768] + bf16 hi/lo split ----------------
__global__ __launch_bounds__(256) void split_k(const float* __restrict__ cat,
                                               __hip_bfloat16* __restrict__ hi,
                                               __hip_bfloat16* __restrict__ lo)
{
  __shared__ float t[64][65];
  const int n0 = blockIdx.x * 64;
  const int c0 = blockIdx.y * 64;
  const int b  = blockIdx.z;
  const int tid = threadIdx.x;
  const int i0 = tid & 63;
  const int q  = tid >> 6;
  const float* p = cat + ((size_t)b * 768 + c0) * 4096 + n0;
#pragma unroll
  for (int k = 0; k < 16; ++k) {
    int cl = q * 16 + k;
    t[cl][i0] = p[(size_t)cl * 4096 + i0];
  }
  __syncthreads();
  size_t ob = ((size_t)b * 4096 + n0) * 768 + c0;
#pragma unroll
  for (int k = 0; k < 16; ++k) {
    int nl = q * 16 + k;
    float v = t[i0][nl];
    __hip_bfloat16 h = __float2bfloat16(v);
    float rem = v - __bfloat162float(h);
    hi[ob + (size_t)nl * 768 + i0] = h;
    lo[ob + (size_t)nl * 768 + i0] = __float2bfloat16(rem);
  }
}

// ---------------- fused sim-max GEMM: per (b,n) max over m of dot*invns[m] ----------------
// grid (N/128, MSPLIT=4, B); block 256 = 4 waves; block tile 128n x 128m; wave 64x64
__global__ __launch_bounds__(256) void simmax_k(
    const unsigned short* __restrict__ Xhi, const unsigned short* __restrict__ Xlo,
    const unsigned short* __restrict__ Shi, const unsigned short* __restrict__ Slo,
    const float* __restrict__ invns, float* __restrict__ partial)
{
  __shared__ unsigned short xh[128][40], xl[128][40], sh[128][40], sl[128][40];
  __shared__ float redbuf[2][128];
  const int tid = threadIdx.x;
  const int lane = tid & 63, wave = tid >> 6;
  const int quad = lane >> 4, l16 = lane & 15;
  const int wn0 = (wave >> 1) * 64;   // n-half within 128-tile
  const int wm0 = (wave & 1) * 64;    // m-half within 128-tile
  const int n0 = blockIdx.x * 128;
  const int ms = blockIdx.y;          // m range [ms*1024, ms*1024+1024)
  const int b  = blockIdx.z;

  const int row = tid >> 2;           // 0..63 (staging)
  const int kk  = (tid & 3) * 8;

  float runmax[4][4];
#pragma unroll
  for (int tn = 0; tn < 4; ++tn)
#pragma unroll
    for (int r = 0; r < 4; ++r) runmax[tn][r] = -1e30f;

  const size_t xbase = ((size_t)b * 4096 + n0) * 768;

  for (int mc = 0; mc < 8; ++mc) {
    const int m0 = ms * 1024 + mc * 128;
    const size_t sbase = ((size_t)b * 4096 + m0) * 768;
    floatv4 acc[4][4];
#pragma unroll
    for (int tn = 0; tn < 4; ++tn)
#pragma unroll
      for (int tm = 0; tm < 4; ++tm) acc[tn][tm] = (floatv4){0.f, 0.f, 0.f, 0.f};

    for (int k0 = 0; k0 < 768; k0 += 32) {
      __syncthreads();
#pragma unroll
      for (int h = 0; h < 2; ++h) {
        int r2 = row + h * 64;
        *(int4*)&xh[r2][kk] = *(const int4*)&Xhi[xbase + (size_t)r2 * 768 + k0 + kk];
        *(int4*)&xl[r2][kk] = *(const int4*)&Xlo[xbase + (size_t)r2 * 768 + k0 + kk];
        *(int4*)&sh[r2][kk] = *(const int4*)&Shi[sbase + (size_t)r2 * 768 + k0 + kk];
        *(int4*)&sl[r2][kk] = *(const int4*)&Slo[sbase + (size_t)r2 * 768 + k0 + kk];
      }
      __syncthreads();
      short8 ah[4], al[4], bh[4], bl[4];
#pragma unroll
      for (int t = 0; t < 4; ++t) {
        ah[t] = *(const short8*)&xh[wn0 + t * 16 + l16][quad * 8];
        al[t] = *(const short8*)&xl[wn0 + t * 16 + l16][quad * 8];
        bh[t] = *(const short8*)&sh[wm0 + t * 16 + l16][quad * 8];
        bl[t] = *(const short8*)&sl[wm0 + t * 16 + l16][quad * 8];
      }
#pragma unroll
      for (int tn = 0; tn < 4; ++tn)
#pragma unroll
        for (int tm = 0; tm < 4; ++tm) {
          acc[tn][tm] = __builtin_amdgcn_mfma_f32_16x16x32_bf16(ah[tn], bh[tm], acc[tn][tm], 0, 0, 0);
          acc[tn][tm] = __builtin_amdgcn_mfma_f32_16x16x32_bf16(ah[tn], bl[tm], acc[tn][tm], 0, 0, 0);
          acc[tn][tm] = __builtin_amdgcn_mfma_f32_16x16x32_bf16(al[tn], bh[tm], acc[tn][tm], 0, 0, 0);
        }
    }
    // fold this m-chunk into running max (scale by invns[m] first)
#pragma unroll
    for (int tm = 0; tm < 4; ++tm) {
      float inv = invns[(size_t)b * 4096 + m0 + wm0 + tm * 16 + l16];
#pragma unroll
      for (int tn = 0; tn < 4; ++tn)
#pragma unroll
        for (int r = 0; r < 4; ++r)
          runmax[tn][r] = fmaxf(runmax[tn][r], acc[tn][tm][r] * inv);
    }
  }

  // reduce max across the 16 lanes sharing a row group
#pragma unroll
  for (int off = 1; off < 16; off <<= 1)
#pragma unroll
    for (int tn = 0; tn < 4; ++tn)
#pragma unroll
      for (int r = 0; r < 4; ++r)
        runmax[tn][r] = fmaxf(runmax[tn][r], __shfl_xor(runmax[tn][r], off, 64));

  if (l16 == 0) {
#pragma unroll
    for (int tn = 0; tn < 4; ++tn)
#pragma unroll
      for (int r = 0; r < 4; ++r)
        redbuf[wave & 1][wn0 + tn * 16 + quad * 4 + r] = runmax[tn][r];
  }
  __syncthreads();
  if (tid < 128) {
    float mx = fmaxf(redbuf[0][tid], redbuf[1][tid]);
    partial[((size_t)ms * 4 + b) * 4096 + n0 + tid] = mx;
  }
}

// ---------------- final: combine MSPLIT partials, apply invnx, mean ----------------
__global__ __launch_bounds__(256) void loss_k(const float* __restrict__ partial,
                                              const float* __restrict__ invnx,
                                              float* __restrict__ out)
{
  float sum = 0.f;
  for (int i = threadIdx.x; i < 16384; i += 256) {
    float mx = partial[i];
    mx = fmaxf(mx, partial[16384 + i]);
    mx = fmaxf(mx, partial[32768 + i]);
    mx = fmaxf(mx, partial[49152 + i]);
    sum += mx * invnx[i];
  }
  __shared__ float red[256];
  red[threadIdx.x] = sum;
  __syncthreads();
  for (int s = 128; s > 0; s >>= 1) {
    if (threadIdx.x < s) red[threadIdx.x] += red[threadIdx.x + s];
    __syncthreads();
  }
  if (threadIdx.x == 0) out[0] = 1.f - red[0] * (1.f / 16384.f);
}

extern "C" void kernel_launch(void* const* d_in, const int* in_sizes, int n_in,
                              void* d_out, int out_size, void* d_ws, size_t ws_size,
                              hipStream_t stream)
{
  const float* outputs = (const float*)d_in[0];
  const float* styles  = (const float*)d_in[1];
  const float* w[7]; const float* bs[7];
  for (int i = 0; i < 7; ++i) { w[i] = (const float*)d_in[2 + 2 * i]; bs[i] = (const float*)d_in[3 + 2 * i]; }

  // workspace layout (floats)
  float* ping   = (float*)d_ws;                 // 16,777,216 f (64 MB region, 4x64x256x256)
  float* pong   = ping + 16777216;
  float* cat_x  = pong + 16777216;              // 4x768x64x64
  float* cat_s  = cat_x + 12582912;
  float* invn_x = cat_s + 12582912;             // 16384
  float* invn_s = invn_x + 16384;
  float* partial = invn_s + 16384;              // 4*16384

  // bf16 hi/lo splits re-use ping/pong space after the VGG passes
  __hip_bfloat16* Xhi = (__hip_bfloat16*)ping;
  __hip_bfloat16* Xlo = Xhi + 12582912;
  __hip_bfloat16* Shi = (__hip_bfloat16*)pong;
  __hip_bfloat16* Slo = Shi + 12582912;

  auto vgg = [&](const float* img, float* cat) {
    conv3x3_k<true ><<<dim3(4, 8, 32),  256, 0, stream>>>(img,  w[0], bs[0], ping, 3,   64,  256, 256, 3,   0,   64,  0);
    conv3x3_k<false><<<dim3(4, 8, 32),  256, 0, stream>>>(ping, w[1], bs[1], pong, 64,  64,  256, 256, 64,  0,   64,  0);
    maxpool2_k<<<dim3(4096), 256, 0, stream>>>(pong, ping, 4 * 64, 256, 256);
    conv3x3_k<false><<<dim3(2, 4, 64),  256, 0, stream>>>(ping, w[2], bs[2], pong, 64,  128, 128, 128, 64,  0,   128, 0);
    conv3x3_k<false><<<dim3(2, 4, 64),  256, 0, stream>>>(pong, w[3], bs[3], ping, 128, 128, 128, 128, 128, 0,   128, 0);
    maxpool2_k<<<dim3(2048), 256, 0, stream>>>(ping, pong, 4 * 128, 128, 128);
    conv3x3_k<false><<<dim3(1, 2, 128), 256, 0, stream>>>(pong, w[4], bs[4], cat,  128, 256, 64,  64,  128, 0,   768, 0);
    conv3x3_k<false><<<dim3(1, 2, 128), 256, 0, stream>>>(cat,  w[5], bs[5], cat,  256, 256, 64,  64,  768, 0,   768, 256);
    conv3x3_k<false><<<dim3(1, 2, 128), 256, 0, stream>>>(cat,  w[6], bs[6], cat,  256, 256, 64,  64,  768, 256, 768, 512);
  };
  vgg(outputs, cat_x);
  vgg(styles,  cat_s);

  norms_k<<<dim3(256), 256, 0, stream>>>(cat_x, invn_x);
  norms_k<<<dim3(256), 256, 0, stream>>>(cat_s, invn_s);
  split_k<<<dim3(64, 12, 4), 256, 0, stream>>>(cat_x, Xhi, Xlo);
  split_k<<<dim3(64, 12, 4), 256, 0, stream>>>(cat_s, Shi, Slo);
  simmax_k<<<dim3(32, 4, 4), 256, 0, stream>>>(
      (const unsigned short*)Xhi, (const unsigned short*)Xlo,
      (const unsigned short*)Shi, (const unsigned short*)Slo,
      invn_s, partial);
  loss_k<<<dim3(1), 256, 0, stream>>>(partial, invn_x, (float*)d_out);
}

// Round 2
// 1486.698 us; speedup vs baseline: 5.4809x; 5.4809x over previous
//
#include <hip/hip_runtime.h>
#include <hip/hip_bf16.h>

__constant__ float c_mean[3] = {0.485f, 0.456f, 0.406f};
__constant__ float c_istd[3] = {1.0f/0.229f, 1.0f/0.224f, 1.0f/0.225f};

typedef __attribute__((ext_vector_type(8))) short short8;
typedef __attribute__((ext_vector_type(4))) short short4v;
typedef __attribute__((ext_vector_type(4))) float floatv4;
typedef unsigned short ushort;

__device__ inline float bf2f(ushort u) {
  unsigned int x = ((unsigned int)u) << 16;
  float f; __builtin_memcpy(&f, &x, 4); return f;
}
__device__ inline ushort f2bf(float f) {
  __hip_bfloat16 h = __float2bfloat16(f);
  ushort u; __builtin_memcpy(&u, &h, 2); return u;
}

// ---------------- weight transform: [OC][IC][3][3] fp32 -> [tap][OC][IC] bf16 hi/lo ----------------
__global__ __launch_bounds__(256) void wtrans_k(const float* __restrict__ w,
                                                ushort* __restrict__ Wh, ushort* __restrict__ Wl,
                                                int OC, int IC)
{
  int t = blockIdx.x * 256 + threadIdx.x;
  int total = OC * IC * 9;
  if (t >= total) return;
  int ic = t % IC; int r = t / IC; int oc = r % OC; int tap = r / OC;
  float v = w[((size_t)oc * IC + ic) * 9 + tap];
  ushort h = f2bf(v);
  Wh[t] = h;
  Wl[t] = f2bf(v - bf2f(h));
}

// ---------------- conv1_1: IC=3 direct fp32, fused norm+bias+relu, out NHWC bf16 hi/lo ----------------
__global__ __launch_bounds__(256) void conv0_k(const float* __restrict__ img,
                                               const float* __restrict__ w,
                                               const float* __restrict__ bias,
                                               ushort* __restrict__ Yh, ushort* __restrict__ Yl)
{
  __shared__ float wl[27][64];
  __shared__ float bl[64];
  const int tid = threadIdx.x;
  for (int i = tid; i < 1728; i += 256) {
    int o = i & 63, t = i >> 6;
    wl[t][o] = w[o * 27 + t];
  }
  if (tid < 64) bl[tid] = bias[tid];
  __syncthreads();
  int px = blockIdx.x * 256 + tid;
  int b = px >> 16, rem = px & 65535;
  int y = rem >> 8, x = rem & 255;
  float iv[27];
#pragma unroll
  for (int c = 0; c < 3; ++c)
#pragma unroll
    for (int dy = 0; dy < 3; ++dy)
#pragma unroll
      for (int dx = 0; dx < 3; ++dx) {
        int gy = y - 1 + dy, gx = x - 1 + dx;
        float v = 0.f;
        if (gy >= 0 && gy < 256 && gx >= 0 && gx < 256)
          v = (img[((size_t)(b * 3 + c) * 256 + gy) * 256 + gx] - c_mean[c]) * c_istd[c];
        iv[c * 9 + dy * 3 + dx] = v;
      }
  float acc[64];
#pragma unroll
  for (int o = 0; o < 64; ++o) acc[o] = 0.f;
#pragma unroll
  for (int t = 0; t < 27; ++t) {
    float v = iv[t];
#pragma unroll
    for (int o = 0; o < 64; ++o) acc[o] = fmaf(v, wl[t][o], acc[o]);
  }
  size_t base = (size_t)px * 64;
#pragma unroll
  for (int o = 0; o < 64; ++o) {
    float v = fmaxf(acc[o] + bl[o], 0.f);
    ushort h = f2bf(v);
    Yh[base + o] = h;
    Yl[base + o] = f2bf(v - bf2f(h));
  }
}

// ---------------- MFMA implicit-GEMM 3x3 conv, NHWC bf16 hi/lo in/out, bias+relu fused ----------------
// TW=16 fixed. Block = 256 thr = 4 waves arranged WPY x WPO; wave tile = 64px x 64oc.
template<int TH, int WPY, int WPO>
__global__ __launch_bounds__(256) void convmf_k(
    const ushort* __restrict__ Xh, const ushort* __restrict__ Xl,
    const ushort* __restrict__ Wh, const ushort* __restrict__ Wl,
    const float* __restrict__ bias,
    ushort* __restrict__ Yh, ushort* __restrict__ Yl,
    int H, int W, int IC, int in_stride, int ic_off,
    int OC, int out_stride, int oc_off, int octiles)
{
  constexpr int HR = TH + 2;
  constexpr int HALO = HR * 18;
  constexpr int OCB = WPO * 64;
  __shared__ ushort xs_h[4 * HALO * 8];
  __shared__ ushort xs_l[4 * HALO * 8];

  const int tid = threadIdx.x;
  const int wave = tid >> 6, lane = tid & 63;
  const int quad = lane >> 4, l16 = lane & 15;
  const int wy = wave / WPO, wo = wave % WPO;
  const int bb = blockIdx.z / octiles, ot = blockIdx.z % octiles;
  const int y0 = blockIdx.y * TH, x0 = blockIdx.x * 16;
  const int ocbase = ot * OCB + wo * 64;   // within layer OC

  floatv4 acc[4][4];
#pragma unroll
  for (int tn = 0; tn < 4; ++tn)
#pragma unroll
    for (int tm = 0; tm < 4; ++tm) acc[tn][tm] = (floatv4){0.f, 0.f, 0.f, 0.f};

  for (int k0 = 0; k0 < IC; k0 += 32) {
    __syncthreads();
    for (int u = tid; u < HALO * 4; u += 256) {
      int px = u >> 2, icq = u & 3;
      int hy = px / 18, hx = px - hy * 18;
      int gy = y0 - 1 + hy, gx = x0 - 1 + hx;
      int4 vh = {0, 0, 0, 0}, vl = {0, 0, 0, 0};
      if (gy >= 0 && gy < H && gx >= 0 && gx < W) {
        size_t g = ((size_t)(bb * H + gy) * W + gx) * in_stride + ic_off + k0 + icq * 8;
        vh = *(const int4*)(Xh + g);
        vl = *(const int4*)(Xl + g);
      }
      *(int4*)&xs_h[(icq * HALO + px) * 8] = vh;
      *(int4*)&xs_l[(icq * HALO + px) * 8] = vl;
    }
    __syncthreads();

#pragma unroll
    for (int tap = 0; tap < 9; ++tap) {
      const int dy = tap / 3, dx = tap % 3;
      short8 bh[4], bl4[4];
#pragma unroll
      for (int tm = 0; tm < 4; ++tm) {
        int oc = ocbase + tm * 16 + l16;
        size_t wg = ((size_t)(tap * OC) + oc) * IC + k0 + quad * 8;
        bh[tm]  = *(const short8*)(Wh + wg);
        bl4[tm] = *(const short8*)(Wl + wg);
      }
#pragma unroll
      for (int tn = 0; tn < 4; ++tn) {
        int p = wy * 64 + tn * 16 + l16;
        int ty = p >> 4, tx = p & 15;
        int hp = (ty + dy) * 18 + tx + dx;
        short8 ah = *(const short8*)&xs_h[(quad * HALO + hp) * 8];
        short8 al = *(const short8*)&xs_l[(quad * HALO + hp) * 8];
#pragma unroll
        for (int tm = 0; tm < 4; ++tm) {
          acc[tn][tm] = __builtin_amdgcn_mfma_f32_16x16x32_bf16(ah, bh[tm],  acc[tn][tm], 0, 0, 0);
          acc[tn][tm] = __builtin_amdgcn_mfma_f32_16x16x32_bf16(ah, bl4[tm], acc[tn][tm], 0, 0, 0);
          acc[tn][tm] = __builtin_amdgcn_mfma_f32_16x16x32_bf16(al, bh[tm],  acc[tn][tm], 0, 0, 0);
        }
      }
    }
  }

#pragma unroll
  for (int tm = 0; tm < 4; ++tm) {
    int ocg = ocbase + tm * 16 + l16;
    float bv = bias[ocg];
#pragma unroll
    for (int tn = 0; tn < 4; ++tn)
#pragma unroll
      for (int r = 0; r < 4; ++r) {
        int p = wy * 64 + tn * 16 + quad * 4 + r;
        int ty = p >> 4, tx = p & 15;
        float v = fmaxf(acc[tn][tm][r] + bv, 0.f);
        ushort h = f2bf(v);
        ushort l = f2bf(v - bf2f(h));
        size_t o = ((size_t)(bb * H + y0 + ty) * W + x0 + tx) * out_stride + oc_off + ocg;
        Yh[o] = h;
        Yl[o] = l;
      }
  }
}

// ---------------- 2x2 maxpool on NHWC hi/lo ----------------
__global__ __launch_bounds__(256) void poolnhwc_k(const ushort* __restrict__ Ih, const ushort* __restrict__ Il,
                                                  ushort* __restrict__ Oh, ushort* __restrict__ Ol,
                                                  int oH, int oW, int C, int total)
{
  int idx = blockIdx.x * 256 + threadIdx.x;
  if (idx >= total) return;
  int C8 = C >> 3;
  int c8 = idx % C8; int t = idx / C8;
  int ox = t % oW; t /= oW;
  int oy = t % oH; int b = t / oH;
  int W2 = oW * 2;
  size_t p00 = ((size_t)(b * 2 * oH + 2 * oy) * W2 + 2 * ox) * C + c8 * 8;
  short8 h00 = *(const short8*)(Ih + p00);
  short8 h01 = *(const short8*)(Ih + p00 + C);
  short8 h10 = *(const short8*)(Ih + p00 + (size_t)W2 * C);
  short8 h11 = *(const short8*)(Ih + p00 + (size_t)W2 * C + C);
  short8 l00 = *(const short8*)(Il + p00);
  short8 l01 = *(const short8*)(Il + p00 + C);
  short8 l10 = *(const short8*)(Il + p00 + (size_t)W2 * C);
  short8 l11 = *(const short8*)(Il + p00 + (size_t)W2 * C + C);
  short8 oh, ol;
#pragma unroll
  for (int j = 0; j < 8; ++j) {
    ushort mh = (ushort)h00[j], ml = (ushort)l00[j];
    float mv = bf2f(mh) + bf2f(ml);
    float v;
    v = bf2f((ushort)h01[j]) + bf2f((ushort)l01[j]);
    if (v > mv) { mv = v; mh = (ushort)h01[j]; ml = (ushort)l01[j]; }
    v = bf2f((ushort)h10[j]) + bf2f((ushort)l10[j]);
    if (v > mv) { mv = v; mh = (ushort)h10[j]; ml = (ushort)l10[j]; }
    v = bf2f((ushort)h11[j]) + bf2f((ushort)l11[j]);
    if (v > mv) { mv = v; mh = (ushort)h11[j]; ml = (ushort)l11[j]; }
    oh[j] = (short)mh; ol[j] = (short)ml;
  }
  size_t po = ((size_t)(b * oH + oy) * oW + ox) * C + c8 * 8;
  *(short8*)(Oh + po) = oh;
  *(short8*)(Ol + po) = ol;
}

// ---------------- per-location inverse norms from NHWC hi/lo cat [16384][768] ----------------
__global__ __launch_bounds__(256) void normsnhwc_k(const ushort* __restrict__ Ch,
                                                   const ushort* __restrict__ Cl,
                                                   float* __restrict__ invn)
{
  int wv = threadIdx.x >> 6, lane = threadIdx.x & 63;
  int n = blockIdx.x * 4 + wv;
  const ushort* ph = Ch + (size_t)n * 768;
  const ushort* pl = Cl + (size_t)n * 768;
  float ssq = 0.f;
#pragma unroll
  for (int j = 0; j < 3; ++j) {
    int off = (lane + 64 * j) * 4;
    short4v h = *(const short4v*)(ph + off);
    short4v l = *(const short4v*)(pl + off);
#pragma unroll
    for (int e = 0; e < 4; ++e) {
      float v = bf2f((ushort)h[e]) + bf2f((ushort)l[e]);
      ssq = fmaf(v, v, ssq);
    }
  }
#pragma unroll
  for (int off = 1; off < 64; off <<= 1)
    ssq += __shfl_xor(ssq, off, 64);
  if (lane == 0) invn[n] = 1.0f / (sqrtf(ssq) + 1e-8f);
}

// ---------------- fused sim-max GEMM (validated round 1) ----------------
__global__ __launch_bounds__(256) void simmax_k(
    const ushort* __restrict__ Xhi, const ushort* __restrict__ Xlo,
    const ushort* __restrict__ Shi, const ushort* __restrict__ Slo,
    const float* __restrict__ invns, float* __restrict__ partial)
{
  __shared__ ushort xh[128][40], xl[128][40], sh[128][40], sl[128][40];
  __shared__ float redbuf[2][128];
  const int tid = threadIdx.x;
  const int lane = tid & 63, wave = tid >> 6;
  const int quad = lane >> 4, l16 = lane & 15;
  const int wn0 = (wave >> 1) * 64;
  const int wm0 = (wave & 1) * 64;
  const int n0 = blockIdx.x * 128;
  const int ms = blockIdx.y;
  const int b  = blockIdx.z;

  const int row = tid >> 2;
  const int kk  = (tid & 3) * 8;

  float runmax[4][4];
#pragma unroll
  for (int tn = 0; tn < 4; ++tn)
#pragma unroll
    for (int r = 0; r < 4; ++r) runmax[tn][r] = -1e30f;

  const size_t xbase = ((size_t)b * 4096 + n0) * 768;

  for (int mc = 0; mc < 8; ++mc) {
    const int m0 = ms * 1024 + mc * 128;
    const size_t sbase = ((size_t)b * 4096 + m0) * 768;
    floatv4 acc[4][4];
#pragma unroll
    for (int tn = 0; tn < 4; ++tn)
#pragma unroll
      for (int tm = 0; tm < 4; ++tm) acc[tn][tm] = (floatv4){0.f, 0.f, 0.f, 0.f};

    for (int k0 = 0; k0 < 768; k0 += 32) {
      __syncthreads();
#pragma unroll
      for (int h = 0; h < 2; ++h) {
        int r2 = row + h * 64;
        *(int4*)&xh[r2][kk] = *(const int4*)&Xhi[xbase + (size_t)r2 * 768 + k0 + kk];
        *(int4*)&xl[r2][kk] = *(const int4*)&Xlo[xbase + (size_t)r2 * 768 + k0 + kk];
        *(int4*)&sh[r2][kk] = *(const int4*)&Shi[sbase + (size_t)r2 * 768 + k0 + kk];
        *(int4*)&sl[r2][kk] = *(const int4*)&Slo[sbase + (size_t)r2 * 768 + k0 + kk];
      }
      __syncthreads();
      short8 ah[4], al[4], bh[4], bl[4];
#pragma unroll
      for (int t = 0; t < 4; ++t) {
        ah[t] = *(const short8*)&xh[wn0 + t * 16 + l16][quad * 8];
        al[t] = *(const short8*)&xl[wn0 + t * 16 + l16][quad * 8];
        bh[t] = *(const short8*)&sh[wm0 + t * 16 + l16][quad * 8];
        bl[t] = *(const short8*)&sl[wm0 + t * 16 + l16][quad * 8];
      }
#pragma unroll
      for (int tn = 0; tn < 4; ++tn)
#pragma unroll
        for (int tm = 0; tm < 4; ++tm) {
          acc[tn][tm] = __builtin_amdgcn_mfma_f32_16x16x32_bf16(ah[tn], bh[tm], acc[tn][tm], 0, 0, 0);
          acc[tn][tm] = __builtin_amdgcn_mfma_f32_16x16x32_bf16(ah[tn], bl[tm], acc[tn][tm], 0, 0, 0);
          acc[tn][tm] = __builtin_amdgcn_mfma_f32_16x16x32_bf16(al[tn], bh[tm], acc[tn][tm], 0, 0, 0);
        }
    }
#pragma unroll
    for (int tm = 0; tm < 4; ++tm) {
      float inv = invns[(size_t)b * 4096 + m0 + wm0 + tm * 16 + l16];
#pragma unroll
      for (int tn = 0; tn < 4; ++tn)
#pragma unroll
        for (int r = 0; r < 4; ++r)
          runmax[tn][r] = fmaxf(runmax[tn][r], acc[tn][tm][r] * inv);
    }
  }

#pragma unroll
  for (int off = 1; off < 16; off <<= 1)
#pragma unroll
    for (int tn = 0; tn < 4; ++tn)
#pragma unroll
      for (int r = 0; r < 4; ++r)
        runmax[tn][r] = fmaxf(runmax[tn][r], __shfl_xor(runmax[tn][r], off, 64));

  if (l16 == 0) {
#pragma unroll
    for (int tn = 0; tn < 4; ++tn)
#pragma unroll
      for (int r = 0; r < 4; ++r)
        redbuf[wave & 1][wn0 + tn * 16 + quad * 4 + r] = runmax[tn][r];
  }
  __syncthreads();
  if (tid < 128) {
    float mx = fmaxf(redbuf[0][tid], redbuf[1][tid]);
    partial[((size_t)ms * 4 + b) * 4096 + n0 + tid] = mx;
  }
}

// ---------------- final: combine MSPLIT partials, apply invnx, mean ----------------
__global__ __launch_bounds__(256) void loss_k(const float* __restrict__ partial,
                                              const float* __restrict__ invnx,
                                              float* __restrict__ out)
{
  float sum = 0.f;
  for (int i = threadIdx.x; i < 16384; i += 256) {
    float mx = partial[i];
    mx = fmaxf(mx, partial[16384 + i]);
    mx = fmaxf(mx, partial[32768 + i]);
    mx = fmaxf(mx, partial[49152 + i]);
    sum += mx * invnx[i];
  }
  __shared__ float red[256];
  red[threadIdx.x] = sum;
  __syncthreads();
  for (int s = 128; s > 0; s >>= 1) {
    if (threadIdx.x < s) red[threadIdx.x] += red[threadIdx.x + s];
    __syncthreads();
  }
  if (threadIdx.x == 0) out[0] = 1.f - red[0] * (1.f / 16384.f);
}

extern "C" void kernel_launch(void* const* d_in, const int* in_sizes, int n_in,
                              void* d_out, int out_size, void* d_ws, size_t ws_size,
                              hipStream_t stream)
{
  const float* outputs = (const float*)d_in[0];
  const float* styles  = (const float*)d_in[1];
  const float* w[7]; const float* bs[7];
  for (int i = 0; i < 7; ++i) { w[i] = (const float*)d_in[2 + 2 * i]; bs[i] = (const float*)d_in[3 + 2 * i]; }

  // ---- workspace layout (ushort units) ----
  ushort* p = (ushort*)d_ws;
  ushort* A_h = p; p += 16777216;     // 4*256*256*64
  ushort* A_l = p; p += 16777216;
  ushort* B_h = p; p += 16777216;
  ushort* B_l = p; p += 16777216;
  ushort* cxh = p; p += 12582912;     // 4*4096*768
  ushort* cxl = p; p += 12582912;
  ushort* csh = p; p += 12582912;
  ushort* csl = p; p += 12582912;
  ushort* W1h = p; p += 36864;  ushort* W1l = p; p += 36864;    // 9*64*64
  ushort* W2h = p; p += 73728;  ushort* W2l = p; p += 73728;    // 9*128*64
  ushort* W3h = p; p += 147456; ushort* W3l = p; p += 147456;   // 9*128*128
  ushort* W4h = p; p += 294912; ushort* W4l = p; p += 294912;   // 9*256*128
  ushort* W5h = p; p += 589824; ushort* W5l = p; p += 589824;   // 9*256*256
  ushort* W6h = p; p += 589824; ushort* W6l = p; p += 589824;
  float* invn_x = (float*)p;
  float* invn_s = invn_x + 16384;
  float* partial = invn_s + 16384;    // 4*16384 floats

  // ---- weight transforms (once) ----
  wtrans_k<<<dim3((9*64*64   + 255)/256), 256, 0, stream>>>(w[1], W1h, W1l, 64, 64);
  wtrans_k<<<dim3((9*128*64  + 255)/256), 256, 0, stream>>>(w[2], W2h, W2l, 128, 64);
  wtrans_k<<<dim3((9*128*128 + 255)/256), 256, 0, stream>>>(w[3], W3h, W3l, 128, 128);
  wtrans_k<<<dim3((9*256*128 + 255)/256), 256, 0, stream>>>(w[4], W4h, W4l, 256, 128);
  wtrans_k<<<dim3((9*256*256 + 255)/256), 256, 0, stream>>>(w[5], W5h, W5l, 256, 256);
  wtrans_k<<<dim3((9*256*256 + 255)/256), 256, 0, stream>>>(w[6], W6h, W6l, 256, 256);

  auto vgg = [&](const float* img, ushort* ch, ushort* cl) {
    conv0_k<<<dim3(1024), 256, 0, stream>>>(img, w[0], bs[0], A_h, A_l);
    convmf_k<16,4,1><<<dim3(16,16,4), 256, 0, stream>>>(A_h,A_l, W1h,W1l, bs[1], B_h,B_l,
        256,256, 64, 64,0,  64, 64,0, 1);
    poolnhwc_k<<<dim3(2048), 256, 0, stream>>>(B_h,B_l, A_h,A_l, 128,128,64, 4*128*128*8);
    convmf_k<8,2,2><<<dim3(8,16,4), 256, 0, stream>>>(A_h,A_l, W2h,W2l, bs[2], B_h,B_l,
        128,128, 64, 64,0, 128, 128,0, 1);
    convmf_k<8,2,2><<<dim3(8,16,4), 256, 0, stream>>>(B_h,B_l, W3h,W3l, bs[3], A_h,A_l,
        128,128, 128, 128,0, 128, 128,0, 1);
    poolnhwc_k<<<dim3(1024), 256, 0, stream>>>(A_h,A_l, B_h,B_l, 64,64,128, 4*64*64*16);
    convmf_k<8,2,2><<<dim3(4,8,8), 256, 0, stream>>>(B_h,B_l, W4h,W4l, bs[4], ch,cl,
        64,64, 128, 128,0, 256, 768,0, 2);
    convmf_k<8,2,2><<<dim3(4,8,8), 256, 0, stream>>>(ch,cl, W5h,W5l, bs[5], ch,cl,
        64,64, 256, 768,0, 256, 768,256, 2);
    convmf_k<8,2,2><<<dim3(4,8,8), 256, 0, stream>>>(ch,cl, W6h,W6l, bs[6], ch,cl,
        64,64, 256, 768,256, 256, 768,512, 2);
  };
  vgg(outputs, cxh, cxl);
  vgg(styles,  csh, csl);

  normsnhwc_k<<<dim3(4096), 256, 0, stream>>>(cxh, cxl, invn_x);
  normsnhwc_k<<<dim3(4096), 256, 0, stream>>>(csh, csl, invn_s);
  simmax_k<<<dim3(32, 4, 4), 256, 0, stream>>>(cxh, cxl, csh, csl, invn_s, partial);
  loss_k<<<dim3(1), 256, 0, stream>>>(partial, invn_x, (float*)d_out);
}

// Round 3
// 1082.520 us; speedup vs baseline: 7.5273x; 1.3734x over previous
//
#include <hip/hip_runtime.h>
#include <hip/hip_bf16.h>

__constant__ float c_mean[3] = {0.485f, 0.456f, 0.406f};
__constant__ float c_istd[3] = {1.0f/0.229f, 1.0f/0.224f, 1.0f/0.225f};

typedef __attribute__((ext_vector_type(8))) short short8;
typedef __attribute__((ext_vector_type(4))) short short4v;
typedef __attribute__((ext_vector_type(4))) float floatv4;
typedef unsigned short ushort;

__device__ inline float bf2f(ushort u) {
  unsigned int x = ((unsigned int)u) << 16;
  float f; __builtin_memcpy(&f, &x, 4); return f;
}
__device__ inline ushort f2bf(float f) {
  __hip_bfloat16 h = __float2bfloat16(f);
  ushort u; __builtin_memcpy(&u, &h, 2); return u;
}

// ---------------- weight transform: [OC][IC][3][3] fp32 -> packed MFMA B-fragments ----------------
// frag id f = (kc*9 + tap)*oct16 + ot ; block of 1024 ushorts: [0:512) hi, [512:1024) lo
// within: lane L (0..63), elem j (0..7): oc = ot*16 + (L&15), ic = kc*32 + (L>>4)*8 + j
__global__ __launch_bounds__(256) void wtrans_k(const float* __restrict__ w,
                                                ushort* __restrict__ Wp,
                                                int OC, int IC)
{
  int t = blockIdx.x * 256 + threadIdx.x;
  int total = OC * IC * 9;
  if (t >= total) return;
  int oct16 = OC >> 4;
  int j = t & 7;
  int L = (t >> 3) & 63;
  int f = t >> 9;
  int ot = f % oct16;
  int r  = f / oct16;
  int tap = r % 9;
  int kc  = r / 9;
  int oc = ot * 16 + (L & 15);
  int ic = kc * 32 + ((L >> 4) << 3) + j;
  float v = w[((size_t)oc * IC + ic) * 9 + tap];
  ushort h = f2bf(v);
  Wp[(size_t)f * 1024 + L * 8 + j]       = h;
  Wp[(size_t)f * 1024 + 512 + L * 8 + j] = f2bf(v - bf2f(h));
}

// ---------------- conv1_1: IC=3 direct fp32, fused norm+bias+relu, out NHWC bf16 hi/lo ----------------
__global__ __launch_bounds__(256) void conv0_k(const float* __restrict__ img,
                                               const float* __restrict__ w,
                                               const float* __restrict__ bias,
                                               ushort* __restrict__ Yh, ushort* __restrict__ Yl)
{
  __shared__ float wl[27][64];
  __shared__ float bl[64];
  const int tid = threadIdx.x;
  for (int i = tid; i < 1728; i += 256) {
    int o = i & 63, t = i >> 6;
    wl[t][o] = w[o * 27 + t];
  }
  if (tid < 64) bl[tid] = bias[tid];
  __syncthreads();
  int px = blockIdx.x * 256 + tid;
  int b = px >> 16, rem = px & 65535;
  int y = rem >> 8, x = rem & 255;
  float iv[27];
#pragma unroll
  for (int c = 0; c < 3; ++c)
#pragma unroll
    for (int dy = 0; dy < 3; ++dy)
#pragma unroll
      for (int dx = 0; dx < 3; ++dx) {
        int gy = y - 1 + dy, gx = x - 1 + dx;
        float v = 0.f;
        if (gy >= 0 && gy < 256 && gx >= 0 && gx < 256)
          v = (img[((size_t)(b * 3 + c) * 256 + gy) * 256 + gx] - c_mean[c]) * c_istd[c];
        iv[c * 9 + dy * 3 + dx] = v;
      }
  float acc[64];
#pragma unroll
  for (int o = 0; o < 64; ++o) acc[o] = 0.f;
#pragma unroll
  for (int t = 0; t < 27; ++t) {
    float v = iv[t];
#pragma unroll
    for (int o = 0; o < 64; ++o) acc[o] = fmaf(v, wl[t][o], acc[o]);
  }
  size_t base = (size_t)px * 64;
#pragma unroll
  for (int o8 = 0; o8 < 8; ++o8) {
    short8 vh, vl;
#pragma unroll
    for (int j = 0; j < 8; ++j) {
      float v = fmaxf(acc[o8 * 8 + j] + bl[o8 * 8 + j], 0.f);
      ushort h = f2bf(v);
      vh[j] = (short)h;
      vl[j] = (short)f2bf(v - bf2f(h));
    }
    *(short8*)(Yh + base + o8 * 8) = vh;
    *(short8*)(Yl + base + o8 * 8) = vl;
  }
}

// ---------------- MFMA implicit-GEMM 3x3 conv, NHWC bf16 hi/lo, bias+relu (+opt fused 2x2 pool) ----
// TW=16 fixed. Block = 256 thr = 4 waves arranged WPY x WPO; wave tile = 64px x 64oc.
template<int TH, int WPY, int WPO, bool POOL>
__global__ __launch_bounds__(256) void convmf_k(
    const ushort* __restrict__ Xh, const ushort* __restrict__ Xl,
    const ushort* __restrict__ Wp,
    const float* __restrict__ bias,
    ushort* __restrict__ Yh, ushort* __restrict__ Yl,
    int H, int W, int IC, int in_stride, int ic_off,
    int OC, int out_stride, int oc_off, int octiles)
{
  constexpr int HR = TH + 2;
  constexpr int HALO = HR * 18;
  constexpr int OCB = WPO * 64;
  __shared__ ushort xs_h[4 * HALO * 8];
  __shared__ ushort xs_l[4 * HALO * 8];

  const int tid = threadIdx.x;
  const int wave = tid >> 6, lane = tid & 63;
  const int quad = lane >> 4, l16 = lane & 15;
  const int wy = wave / WPO, wo = wave % WPO;
  const int bb = blockIdx.z / octiles, ot = blockIdx.z % octiles;
  const int y0 = blockIdx.y * TH, x0 = blockIdx.x * 16;
  const int ocbase = ot * OCB + wo * 64;   // within layer OC
  const int oct16 = OC >> 4;

  floatv4 acc[4][4];
#pragma unroll
  for (int tn = 0; tn < 4; ++tn)
#pragma unroll
    for (int tm = 0; tm < 4; ++tm) acc[tn][tm] = (floatv4){0.f, 0.f, 0.f, 0.f};

  for (int k0 = 0; k0 < IC; k0 += 32) {
    __syncthreads();
    for (int u = tid; u < HALO * 4; u += 256) {
      int px = u >> 2, icq = u & 3;
      int hy = px / 18, hx = px - hy * 18;
      int gy = y0 - 1 + hy, gx = x0 - 1 + hx;
      int4 vh = {0, 0, 0, 0}, vl = {0, 0, 0, 0};
      if (gy >= 0 && gy < H && gx >= 0 && gx < W) {
        size_t g = ((size_t)(bb * H + gy) * W + gx) * in_stride + ic_off + k0 + icq * 8;
        vh = *(const int4*)(Xh + g);
        vl = *(const int4*)(Xl + g);
      }
      *(int4*)&xs_h[(icq * HALO + px) * 8] = vh;
      *(int4*)&xs_l[(icq * HALO + px) * 8] = vl;
    }
    __syncthreads();

#pragma unroll
    for (int tap = 0; tap < 9; ++tap) {
      const int dy = tap / 3, dx = tap % 3;
      // packed B fragments: contiguous 1KB per fragment, coalesced wave load
      const size_t wg = (((size_t)(k0 >> 5) * 9 + tap) * oct16 + (ocbase >> 4)) * 1024 + (size_t)lane * 8;
      short8 bh[4], bl4[4];
#pragma unroll
      for (int tm = 0; tm < 4; ++tm) {
        bh[tm]  = *(const short8*)(Wp + wg + tm * 1024);
        bl4[tm] = *(const short8*)(Wp + wg + tm * 1024 + 512);
      }
#pragma unroll
      for (int tn = 0; tn < 4; ++tn) {
        int p = wy * 64 + tn * 16 + l16;
        int ty = p >> 4, tx = p & 15;
        int hp = (ty + dy) * 18 + tx + dx;
        short8 ah = *(const short8*)&xs_h[(quad * HALO + hp) * 8];
        short8 al = *(const short8*)&xs_l[(quad * HALO + hp) * 8];
#pragma unroll
        for (int tm = 0; tm < 4; ++tm) {
          acc[tn][tm] = __builtin_amdgcn_mfma_f32_16x16x32_bf16(ah, bh[tm],  acc[tn][tm], 0, 0, 0);
          acc[tn][tm] = __builtin_amdgcn_mfma_f32_16x16x32_bf16(ah, bl4[tm], acc[tn][tm], 0, 0, 0);
          acc[tn][tm] = __builtin_amdgcn_mfma_f32_16x16x32_bf16(al, bh[tm],  acc[tn][tm], 0, 0, 0);
        }
      }
    }
  }

  if (POOL) {
    // C/D layout: row(pixel) = quad... NOTE pixel p = wy*64 + tn*16 + quad*4 + r
    // -> ty = wy*4 + tn (row pairs = tn pairs), tx = quad*4 + r (col pairs = r pairs):
    // 2x2 pooling is thread-local.
    const int oH = H >> 1, oW = W >> 1;
#pragma unroll
    for (int tm = 0; tm < 4; ++tm) {
      int ocg = ocbase + tm * 16 + l16;
      float bv = bias[ocg];
#pragma unroll
      for (int tn2 = 0; tn2 < 2; ++tn2)
#pragma unroll
        for (int r2 = 0; r2 < 2; ++r2) {
          float v0 = fmaxf(acc[2 * tn2][tm][2 * r2]     + bv, 0.f);
          float v1 = fmaxf(acc[2 * tn2][tm][2 * r2 + 1] + bv, 0.f);
          float v2 = fmaxf(acc[2 * tn2 + 1][tm][2 * r2]     + bv, 0.f);
          float v3 = fmaxf(acc[2 * tn2 + 1][tm][2 * r2 + 1] + bv, 0.f);
          float v = fmaxf(fmaxf(v0, v1), fmaxf(v2, v3));
          ushort h = f2bf(v);
          ushort l = f2bf(v - bf2f(h));
          int oy = (y0 >> 1) + wy * 2 + tn2;
          int ox = (x0 >> 1) + quad * 2 + r2;
          size_t o = ((size_t)(bb * oH + oy) * oW + ox) * out_stride + oc_off + ocg;
          Yh[o] = h;
          Yl[o] = l;
        }
    }
  } else {
#pragma unroll
    for (int tm = 0; tm < 4; ++tm) {
      int ocg = ocbase + tm * 16 + l16;
      float bv = bias[ocg];
#pragma unroll
      for (int tn = 0; tn < 4; ++tn)
#pragma unroll
        for (int r = 0; r < 4; ++r) {
          int p = wy * 64 + tn * 16 + quad * 4 + r;
          int ty = p >> 4, tx = p & 15;
          float v = fmaxf(acc[tn][tm][r] + bv, 0.f);
          ushort h = f2bf(v);
          ushort l = f2bf(v - bf2f(h));
          size_t o = ((size_t)(bb * H + y0 + ty) * W + x0 + tx) * out_stride + oc_off + ocg;
          Yh[o] = h;
          Yl[o] = l;
        }
    }
  }
}

// ---------------- per-location inverse norms from NHWC hi/lo cat [16384][768] ----------------
__global__ __launch_bounds__(256) void normsnhwc_k(const ushort* __restrict__ Ch,
                                                   const ushort* __restrict__ Cl,
                                                   float* __restrict__ invn)
{
  int wv = threadIdx.x >> 6, lane = threadIdx.x & 63;
  int n = blockIdx.x * 4 + wv;
  const ushort* ph = Ch + (size_t)n * 768;
  const ushort* pl = Cl + (size_t)n * 768;
  float ssq = 0.f;
#pragma unroll
  for (int j = 0; j < 3; ++j) {
    int off = (lane + 64 * j) * 4;
    short4v h = *(const short4v*)(ph + off);
    short4v l = *(const short4v*)(pl + off);
#pragma unroll
    for (int e = 0; e < 4; ++e) {
      float v = bf2f((ushort)h[e]) + bf2f((ushort)l[e]);
      ssq = fmaf(v, v, ssq);
    }
  }
#pragma unroll
  for (int off = 1; off < 64; off <<= 1)
    ssq += __shfl_xor(ssq, off, 64);
  if (lane == 0) invn[n] = 1.0f / (sqrtf(ssq) + 1e-8f);
}

// ---------------- fused sim-max GEMM (validated) ----------------
__global__ __launch_bounds__(256) void simmax_k(
    const ushort* __restrict__ Xhi, const ushort* __restrict__ Xlo,
    const ushort* __restrict__ Shi, const ushort* __restrict__ Slo,
    const float* __restrict__ invns, float* __restrict__ partial)
{
  __shared__ ushort xh[128][40], xl[128][40], sh[128][40], sl[128][40];
  __shared__ float redbuf[2][128];
  const int tid = threadIdx.x;
  const int lane = tid & 63, wave = tid >> 6;
  const int quad = lane >> 4, l16 = lane & 15;
  const int wn0 = (wave >> 1) * 64;
  const int wm0 = (wave & 1) * 64;
  const int n0 = blockIdx.x * 128;
  const int ms = blockIdx.y;
  const int b  = blockIdx.z;

  const int row = tid >> 2;
  const int kk  = (tid & 3) * 8;

  float runmax[4][4];
#pragma unroll
  for (int tn = 0; tn < 4; ++tn)
#pragma unroll
    for (int r = 0; r < 4; ++r) runmax[tn][r] = -1e30f;

  const size_t xbase = ((size_t)b * 4096 + n0) * 768;

  for (int mc = 0; mc < 8; ++mc) {
    const int m0 = ms * 1024 + mc * 128;
    const size_t sbase = ((size_t)b * 4096 + m0) * 768;
    floatv4 acc[4][4];
#pragma unroll
    for (int tn = 0; tn < 4; ++tn)
#pragma unroll
      for (int tm = 0; tm < 4; ++tm) acc[tn][tm] = (floatv4){0.f, 0.f, 0.f, 0.f};

    for (int k0 = 0; k0 < 768; k0 += 32) {
      __syncthreads();
#pragma unroll
      for (int h = 0; h < 2; ++h) {
        int r2 = row + h * 64;
        *(int4*)&xh[r2][kk] = *(const int4*)&Xhi[xbase + (size_t)r2 * 768 + k0 + kk];
        *(int4*)&xl[r2][kk] = *(const int4*)&Xlo[xbase + (size_t)r2 * 768 + k0 + kk];
        *(int4*)&sh[r2][kk] = *(const int4*)&Shi[sbase + (size_t)r2 * 768 + k0 + kk];
        *(int4*)&sl[r2][kk] = *(const int4*)&Slo[sbase + (size_t)r2 * 768 + k0 + kk];
      }
      __syncthreads();
      short8 ah[4], al[4], bh[4], bl[4];
#pragma unroll
      for (int t = 0; t < 4; ++t) {
        ah[t] = *(const short8*)&xh[wn0 + t * 16 + l16][quad * 8];
        al[t] = *(const short8*)&xl[wn0 + t * 16 + l16][quad * 8];
        bh[t] = *(const short8*)&sh[wm0 + t * 16 + l16][quad * 8];
        bl[t] = *(const short8*)&sl[wm0 + t * 16 + l16][quad * 8];
      }
#pragma unroll
      for (int tn = 0; tn < 4; ++tn)
#pragma unroll
        for (int tm = 0; tm < 4; ++tm) {
          acc[tn][tm] = __builtin_amdgcn_mfma_f32_16x16x32_bf16(ah[tn], bh[tm], acc[tn][tm], 0, 0, 0);
          acc[tn][tm] = __builtin_amdgcn_mfma_f32_16x16x32_bf16(ah[tn], bl[tm], acc[tn][tm], 0, 0, 0);
          acc[tn][tm] = __builtin_amdgcn_mfma_f32_16x16x32_bf16(al[tn], bh[tm], acc[tn][tm], 0, 0, 0);
        }
    }
#pragma unroll
    for (int tm = 0; tm < 4; ++tm) {
      float inv = invns[(size_t)b * 4096 + m0 + wm0 + tm * 16 + l16];
#pragma unroll
      for (int tn = 0; tn < 4; ++tn)
#pragma unroll
        for (int r = 0; r < 4; ++r)
          runmax[tn][r] = fmaxf(runmax[tn][r], acc[tn][tm][r] * inv);
    }
  }

#pragma unroll
  for (int off = 1; off < 16; off <<= 1)
#pragma unroll
    for (int tn = 0; tn < 4; ++tn)
#pragma unroll
      for (int r = 0; r < 4; ++r)
        runmax[tn][r] = fmaxf(runmax[tn][r], __shfl_xor(runmax[tn][r], off, 64));

  if (l16 == 0) {
#pragma unroll
    for (int tn = 0; tn < 4; ++tn)
#pragma unroll
      for (int r = 0; r < 4; ++r)
        redbuf[wave & 1][wn0 + tn * 16 + quad * 4 + r] = runmax[tn][r];
  }
  __syncthreads();
  if (tid < 128) {
    float mx = fmaxf(redbuf[0][tid], redbuf[1][tid]);
    partial[((size_t)ms * 4 + b) * 4096 + n0 + tid] = mx;
  }
}

// ---------------- final: combine MSPLIT partials, apply invnx, mean ----------------
__global__ __launch_bounds__(256) void loss_k(const float* __restrict__ partial,
                                              const float* __restrict__ invnx,
                                              float* __restrict__ out)
{
  float sum = 0.f;
  for (int i = threadIdx.x; i < 16384; i += 256) {
    float mx = partial[i];
    mx = fmaxf(mx, partial[16384 + i]);
    mx = fmaxf(mx, partial[32768 + i]);
    mx = fmaxf(mx, partial[49152 + i]);
    sum += mx * invnx[i];
  }
  __shared__ float red[256];
  red[threadIdx.x] = sum;
  __syncthreads();
  for (int s = 128; s > 0; s >>= 1) {
    if (threadIdx.x < s) red[threadIdx.x] += red[threadIdx.x + s];
    __syncthreads();
  }
  if (threadIdx.x == 0) out[0] = 1.f - red[0] * (1.f / 16384.f);
}

extern "C" void kernel_launch(void* const* d_in, const int* in_sizes, int n_in,
                              void* d_out, int out_size, void* d_ws, size_t ws_size,
                              hipStream_t stream)
{
  const float* outputs = (const float*)d_in[0];
  const float* styles  = (const float*)d_in[1];
  const float* w[7]; const float* bs[7];
  for (int i = 0; i < 7; ++i) { w[i] = (const float*)d_in[2 + 2 * i]; bs[i] = (const float*)d_in[3 + 2 * i]; }

  // ---- workspace layout (ushort units) ----
  ushort* p = (ushort*)d_ws;
  ushort* A_h = p; p += 16777216;     // 4*256*256*64
  ushort* A_l = p; p += 16777216;
  ushort* B_h = p; p += 16777216;
  ushort* B_l = p; p += 16777216;
  ushort* cxh = p; p += 12582912;     // 4*4096*768
  ushort* cxl = p; p += 12582912;
  ushort* csh = p; p += 12582912;
  ushort* csl = p; p += 12582912;
  ushort* W1p = p; p += 73728;        // 9*64*64*2  (hi+lo packed fragments)
  ushort* W2p = p; p += 147456;       // 9*128*64*2
  ushort* W3p = p; p += 294912;       // 9*128*128*2
  ushort* W4p = p; p += 589824;       // 9*256*128*2
  ushort* W5p = p; p += 1179648;      // 9*256*256*2
  ushort* W6p = p; p += 1179648;
  float* invn_x = (float*)p;
  float* invn_s = invn_x + 16384;
  float* partial = invn_s + 16384;    // 4*16384 floats

  // ---- weight transforms (packed fragment layout) ----
  wtrans_k<<<dim3((9*64*64   + 255)/256), 256, 0, stream>>>(w[1], W1p, 64, 64);
  wtrans_k<<<dim3((9*128*64  + 255)/256), 256, 0, stream>>>(w[2], W2p, 128, 64);
  wtrans_k<<<dim3((9*128*128 + 255)/256), 256, 0, stream>>>(w[3], W3p, 128, 128);
  wtrans_k<<<dim3((9*256*128 + 255)/256), 256, 0, stream>>>(w[4], W4p, 256, 128);
  wtrans_k<<<dim3((9*256*256 + 255)/256), 256, 0, stream>>>(w[5], W5p, 256, 256);
  wtrans_k<<<dim3((9*256*256 + 255)/256), 256, 0, stream>>>(w[6], W6p, 256, 256);

  auto vgg = [&](const float* img, ushort* ch, ushort* cl) {
    conv0_k<<<dim3(1024), 256, 0, stream>>>(img, w[0], bs[0], A_h, A_l);
    // conv1_2 + fused pool: 256x256x64 -> 128x128x64
    convmf_k<16,4,1,true><<<dim3(16,16,4), 256, 0, stream>>>(A_h,A_l, W1p, bs[1], B_h,B_l,
        256,256, 64, 64,0,  64, 64,0, 1);
    // conv2_1: 128x128x64 -> 128x128x128
    convmf_k<8,2,2,false><<<dim3(8,16,4), 256, 0, stream>>>(B_h,B_l, W2p, bs[2], A_h,A_l,
        128,128, 64, 64,0, 128, 128,0, 1);
    // conv2_2 + fused pool: 128x128x128 -> 64x64x128
    convmf_k<8,2,2,true><<<dim3(8,16,4), 256, 0, stream>>>(A_h,A_l, W3p, bs[3], B_h,B_l,
        128,128, 128, 128,0, 128, 128,0, 1);
    // conv3_1: 64x64x128 -> cat[..,0:256]
    convmf_k<8,2,2,false><<<dim3(4,8,8), 256, 0, stream>>>(B_h,B_l, W4p, bs[4], ch,cl,
        64,64, 128, 128,0, 256, 768,0, 2);
    convmf_k<8,2,2,false><<<dim3(4,8,8), 256, 0, stream>>>(ch,cl, W5p, bs[5], ch,cl,
        64,64, 256, 768,0, 256, 768,256, 2);
    convmf_k<8,2,2,false><<<dim3(4,8,8), 256, 0, stream>>>(ch,cl, W6p, bs[6], ch,cl,
        64,64, 256, 768,256, 256, 768,512, 2);
  };
  vgg(outputs, cxh, cxl);
  vgg(styles,  csh, csl);

  normsnhwc_k<<<dim3(4096), 256, 0, stream>>>(cxh, cxl, invn_x);
  normsnhwc_k<<<dim3(4096), 256, 0, stream>>>(csh, csl, invn_s);
  simmax_k<<<dim3(32, 4, 4), 256, 0, stream>>>(cxh, cxl, csh, csl, invn_s, partial);
  loss_k<<<dim3(1), 256, 0, stream>>>(partial, invn_x, (float*)d_out);
}

// Round 4
// 961.400 us; speedup vs baseline: 8.4756x; 1.1260x over previous
//
#include <hip/hip_runtime.h>
#include <hip/hip_bf16.h>

__constant__ float c_mean[3] = {0.485f, 0.456f, 0.406f};
__constant__ float c_istd[3] = {1.0f/0.229f, 1.0f/0.224f, 1.0f/0.225f};

typedef __attribute__((ext_vector_type(8))) short short8;
typedef __attribute__((ext_vector_type(4))) float floatv4;
typedef unsigned short ushort;

__device__ inline float bf2f(ushort u) {
  unsigned int x = ((unsigned int)u) << 16;
  float f; __builtin_memcpy(&f, &x, 4); return f;
}
__device__ inline ushort f2bf(float f) {
  __hip_bfloat16 h = __float2bfloat16(f);
  ushort u; __builtin_memcpy(&u, &h, 2); return u;
}

// ---------------- zero ssq accumulators ----------------
__global__ __launch_bounds__(256) void zero_k(float* __restrict__ p, int n)
{
  int i = blockIdx.x * 256 + threadIdx.x;
  if (i < n) p[i] = 0.f;
}

// ---------------- weight transform: [OC][IC][3][3] fp32 -> packed MFMA B-fragments ----------------
// frag f = (kc*9 + tap)*oct16 + ot ; 1024-ushort block: [0:512) hi, [512:1024) lo
// lane L, elem j: oc = ot*16 + (L&15), ic = kc*32 + (L>>4)*8 + j
__global__ __launch_bounds__(256) void wtrans_k(const float* __restrict__ w,
                                                ushort* __restrict__ Wp,
                                                int OC, int IC)
{
  int t = blockIdx.x * 256 + threadIdx.x;
  int total = OC * IC * 9;
  if (t >= total) return;
  int oct16 = OC >> 4;
  int j = t & 7;
  int L = (t >> 3) & 63;
  int f = t >> 9;
  int ot = f % oct16;
  int r  = f / oct16;
  int tap = r % 9;
  int kc  = r / 9;
  int oc = ot * 16 + (L & 15);
  int ic = kc * 32 + ((L >> 4) << 3) + j;
  float v = w[((size_t)oc * IC + ic) * 9 + tap];
  ushort h = f2bf(v);
  Wp[(size_t)f * 1024 + L * 8 + j]       = h;
  Wp[(size_t)f * 1024 + 512 + L * 8 + j] = f2bf(v - bf2f(h));
}

// ---------------- conv1_1: IC=3 direct fp32, fused norm+bias+relu, out NHWC bf16 hi/lo ----------------
__global__ __launch_bounds__(256) void conv0_k(const float* __restrict__ img,
                                               const float* __restrict__ w,
                                               const float* __restrict__ bias,
                                               ushort* __restrict__ Yh, ushort* __restrict__ Yl)
{
  __shared__ float wl[27][64];
  __shared__ float bl[64];
  const int tid = threadIdx.x;
  for (int i = tid; i < 1728; i += 256) {
    int o = i & 63, t = i >> 6;
    wl[t][o] = w[o * 27 + t];
  }
  if (tid < 64) bl[tid] = bias[tid];
  __syncthreads();
  int px = blockIdx.x * 256 + tid;
  int b = px >> 16, rem = px & 65535;
  int y = rem >> 8, x = rem & 255;
  float iv[27];
#pragma unroll
  for (int c = 0; c < 3; ++c)
#pragma unroll
    for (int dy = 0; dy < 3; ++dy)
#pragma unroll
      for (int dx = 0; dx < 3; ++dx) {
        int gy = y - 1 + dy, gx = x - 1 + dx;
        float v = 0.f;
        if (gy >= 0 && gy < 256 && gx >= 0 && gx < 256)
          v = (img[((size_t)(b * 3 + c) * 256 + gy) * 256 + gx] - c_mean[c]) * c_istd[c];
        iv[c * 9 + dy * 3 + dx] = v;
      }
  float acc[64];
#pragma unroll
  for (int o = 0; o < 64; ++o) acc[o] = 0.f;
#pragma unroll
  for (int t = 0; t < 27; ++t) {
    float v = iv[t];
#pragma unroll
    for (int o = 0; o < 64; ++o) acc[o] = fmaf(v, wl[t][o], acc[o]);
  }
  size_t base = (size_t)px * 64;
#pragma unroll
  for (int o8 = 0; o8 < 8; ++o8) {
    short8 vh, vl;
#pragma unroll
    for (int j = 0; j < 8; ++j) {
      float v = fmaxf(acc[o8 * 8 + j] + bl[o8 * 8 + j], 0.f);
      ushort h = f2bf(v);
      vh[j] = (short)h;
      vl[j] = (short)f2bf(v - bf2f(h));
    }
    *(short8*)(Yh + base + o8 * 8) = vh;
    *(short8*)(Yl + base + o8 * 8) = vl;
  }
}

// ---------------- MFMA implicit-GEMM 3x3 conv, NHWC bf16 hi/lo, bias+relu (+pool / +ssq) ----------
// Block = 256 thr = 4 waves WPY x WPO; wave tile = 64px x 64oc; px tile = TH x 16.
template<int TH, int WPY, int WPO, bool POOL, bool SSQ>
__global__ __launch_bounds__(256) void convmf_k(
    const ushort* __restrict__ Xh, const ushort* __restrict__ Xl,
    const ushort* __restrict__ Wp,
    const float* __restrict__ bias,
    ushort* __restrict__ Yh, ushort* __restrict__ Yl,
    float* __restrict__ ssq,
    int H, int W, int IC, int in_stride, int ic_off,
    int OC, int out_stride, int oc_off, int octiles)
{
  constexpr int HR = TH + 2;
  constexpr int HALO = HR * 18;
  constexpr int OCB = WPO * 64;
  __shared__ ushort xs_h[4 * HALO * 8];
  __shared__ ushort xs_l[4 * HALO * 8];

  const int tid = threadIdx.x;
  const int wave = tid >> 6, lane = tid & 63;
  const int quad = lane >> 4, l16 = lane & 15;
  const int wy = wave / WPO, wo = wave % WPO;
  const int bb = blockIdx.z / octiles, ot = blockIdx.z % octiles;
  const int y0 = blockIdx.y * TH, x0 = blockIdx.x * 16;
  const int ocbase = ot * OCB + wo * 64;
  const int oct16 = OC >> 4;

  floatv4 acc[4][4];
#pragma unroll
  for (int tn = 0; tn < 4; ++tn)
#pragma unroll
    for (int tm = 0; tm < 4; ++tm) acc[tn][tm] = (floatv4){0.f, 0.f, 0.f, 0.f};

  for (int k0 = 0; k0 < IC; k0 += 32) {
    __syncthreads();
    for (int u = tid; u < HALO * 4; u += 256) {
      int px = u >> 2, icq = u & 3;
      int hy = px / 18, hx = px - hy * 18;
      int gy = y0 - 1 + hy, gx = x0 - 1 + hx;
      int4 vh = {0, 0, 0, 0}, vl = {0, 0, 0, 0};
      if (gy >= 0 && gy < H && gx >= 0 && gx < W) {
        size_t g = ((size_t)(bb * H + gy) * W + gx) * in_stride + ic_off + k0 + icq * 8;
        vh = *(const int4*)(Xh + g);
        vl = *(const int4*)(Xl + g);
      }
      *(int4*)&xs_h[(icq * HALO + px) * 8] = vh;
      *(int4*)&xs_l[(icq * HALO + px) * 8] = vl;
    }
    __syncthreads();

#pragma unroll
    for (int tap = 0; tap < 9; ++tap) {
      const int dy = tap / 3, dx = tap % 3;
      const size_t wg = (((size_t)(k0 >> 5) * 9 + tap) * oct16 + (ocbase >> 4)) * 1024 + (size_t)lane * 8;
      short8 bh[4], bl4[4];
#pragma unroll
      for (int tm = 0; tm < 4; ++tm) {
        bh[tm]  = *(const short8*)(Wp + wg + tm * 1024);
        bl4[tm] = *(const short8*)(Wp + wg + tm * 1024 + 512);
      }
#pragma unroll
      for (int tn = 0; tn < 4; ++tn) {
        int p = wy * 64 + tn * 16 + l16;
        int ty = p >> 4, tx = p & 15;
        int hp = (ty + dy) * 18 + tx + dx;
        short8 ah = *(const short8*)&xs_h[(quad * HALO + hp) * 8];
        short8 al = *(const short8*)&xs_l[(quad * HALO + hp) * 8];
#pragma unroll
        for (int tm = 0; tm < 4; ++tm) {
          acc[tn][tm] = __builtin_amdgcn_mfma_f32_16x16x32_bf16(ah, bh[tm],  acc[tn][tm], 0, 0, 0);
          acc[tn][tm] = __builtin_amdgcn_mfma_f32_16x16x32_bf16(ah, bl4[tm], acc[tn][tm], 0, 0, 0);
          acc[tn][tm] = __builtin_amdgcn_mfma_f32_16x16x32_bf16(al, bh[tm],  acc[tn][tm], 0, 0, 0);
        }
      }
    }
  }

  if (POOL) {
    // px p = wy*64 + tn*16 + quad*4 + r -> ty = wy*4+tn, tx = quad*4+r: 2x2 pool thread-local
    const int oH = H >> 1, oW = W >> 1;
#pragma unroll
    for (int tm = 0; tm < 4; ++tm) {
      int ocg = ocbase + tm * 16 + l16;
      float bv = bias[ocg];
#pragma unroll
      for (int tn2 = 0; tn2 < 2; ++tn2)
#pragma unroll
        for (int r2 = 0; r2 < 2; ++r2) {
          float v0 = fmaxf(acc[2 * tn2][tm][2 * r2]     + bv, 0.f);
          float v1 = fmaxf(acc[2 * tn2][tm][2 * r2 + 1] + bv, 0.f);
          float v2 = fmaxf(acc[2 * tn2 + 1][tm][2 * r2]     + bv, 0.f);
          float v3 = fmaxf(acc[2 * tn2 + 1][tm][2 * r2 + 1] + bv, 0.f);
          float v = fmaxf(fmaxf(v0, v1), fmaxf(v2, v3));
          ushort h = f2bf(v);
          ushort l = f2bf(v - bf2f(h));
          int oy = (y0 >> 1) + wy * 2 + tn2;
          int ox = (x0 >> 1) + quad * 2 + r2;
          size_t o = ((size_t)(bb * oH + oy) * oW + ox) * out_stride + oc_off + ocg;
          Yh[o] = h;
          Yl[o] = l;
        }
    }
  } else {
    float sv[4][4];
    if (SSQ) {
#pragma unroll
      for (int tn = 0; tn < 4; ++tn)
#pragma unroll
        for (int r = 0; r < 4; ++r) sv[tn][r] = 0.f;
    }
#pragma unroll
    for (int tm = 0; tm < 4; ++tm) {
      int ocg = ocbase + tm * 16 + l16;
      float bv = bias[ocg];
#pragma unroll
      for (int tn = 0; tn < 4; ++tn)
#pragma unroll
        for (int r = 0; r < 4; ++r) {
          int p = wy * 64 + tn * 16 + quad * 4 + r;
          int ty = p >> 4, tx = p & 15;
          float v = fmaxf(acc[tn][tm][r] + bv, 0.f);
          if (SSQ) sv[tn][r] = fmaf(v, v, sv[tn][r]);
          ushort h = f2bf(v);
          ushort l = f2bf(v - bf2f(h));
          size_t o = ((size_t)(bb * H + y0 + ty) * W + x0 + tx) * out_stride + oc_off + ocg;
          Yh[o] = h;
          Yl[o] = l;
        }
    }
    if (SSQ) {
      // sum the 64-oc slice over the 16 lanes sharing a px; one atomic per px per wave
#pragma unroll
      for (int tn = 0; tn < 4; ++tn)
#pragma unroll
        for (int r = 0; r < 4; ++r) {
          float s = sv[tn][r];
          s += __shfl_xor(s, 1, 64);
          s += __shfl_xor(s, 2, 64);
          s += __shfl_xor(s, 4, 64);
          s += __shfl_xor(s, 8, 64);
          if (l16 == 0) {
            int p = wy * 64 + tn * 16 + quad * 4 + r;
            int ty = p >> 4, tx = p & 15;
            atomicAdd(&ssq[(size_t)bb * 4096 + (y0 + ty) * 64 + x0 + tx], s);
          }
        }
    }
  }
}

// ---------------- finalize: ssq -> 1/(sqrt+eps) in place ----------------
__global__ __launch_bounds__(256) void finalize_k(float* __restrict__ p, int n)
{
  int i = blockIdx.x * 256 + threadIdx.x;
  if (i < n) p[i] = 1.0f / (sqrtf(p[i]) + 1e-8f);
}

// ---------------- fused sim-max GEMM: X = cat[b], S = cat[b+4] ----------------
// grid (32, 8, 4); block 256 = 4 waves; block tile 128n x 128m; ms-chunk = 512 m
__global__ __launch_bounds__(256) void simmax_k(
    const ushort* __restrict__ Ch, const ushort* __restrict__ Cl,
    const float* __restrict__ invns, float* __restrict__ partial)
{
  __shared__ ushort xh[128][36], xl[128][36], sh[128][36], sl[128][36];
  __shared__ float redbuf[2][128];
  const int tid = threadIdx.x;
  const int lane = tid & 63, wave = tid >> 6;
  const int quad = lane >> 4, l16 = lane & 15;
  const int wn0 = (wave >> 1) * 64;
  const int wm0 = (wave & 1) * 64;
  const int n0 = blockIdx.x * 128;
  const int ms = blockIdx.y;
  const int b  = blockIdx.z;

  const int row = tid >> 2;
  const int kk  = (tid & 3) * 8;

  float runmax[4][4];
#pragma unroll
  for (int tn = 0; tn < 4; ++tn)
#pragma unroll
    for (int r = 0; r < 4; ++r) runmax[tn][r] = -1e30f;

  const size_t xbase = ((size_t)b * 4096 + n0) * 768;

  for (int mc = 0; mc < 4; ++mc) {
    const int m0 = ms * 512 + mc * 128;
    const size_t sbase = ((size_t)(b + 4) * 4096 + m0) * 768;
    floatv4 acc[4][4];
#pragma unroll
    for (int tn = 0; tn < 4; ++tn)
#pragma unroll
      for (int tm = 0; tm < 4; ++tm) acc[tn][tm] = (floatv4){0.f, 0.f, 0.f, 0.f};

    for (int k0 = 0; k0 < 768; k0 += 32) {
      __syncthreads();
#pragma unroll
      for (int h = 0; h < 2; ++h) {
        int r2 = row + h * 64;
        *(int4*)&xh[r2][kk] = *(const int4*)&Ch[xbase + (size_t)r2 * 768 + k0 + kk];
        *(int4*)&xl[r2][kk] = *(const int4*)&Cl[xbase + (size_t)r2 * 768 + k0 + kk];
        *(int4*)&sh[r2][kk] = *(const int4*)&Ch[sbase + (size_t)r2 * 768 + k0 + kk];
        *(int4*)&sl[r2][kk] = *(const int4*)&Cl[sbase + (size_t)r2 * 768 + k0 + kk];
      }
      __syncthreads();
      short8 ah[4], al[4], bh[4], bl[4];
#pragma unroll
      for (int t = 0; t < 4; ++t) {
        ah[t] = *(const short8*)&xh[wn0 + t * 16 + l16][quad * 8];
        al[t] = *(const short8*)&xl[wn0 + t * 16 + l16][quad * 8];
        bh[t] = *(const short8*)&sh[wm0 + t * 16 + l16][quad * 8];
        bl[t] = *(const short8*)&sl[wm0 + t * 16 + l16][quad * 8];
      }
#pragma unroll
      for (int tn = 0; tn < 4; ++tn)
#pragma unroll
        for (int tm = 0; tm < 4; ++tm) {
          acc[tn][tm] = __builtin_amdgcn_mfma_f32_16x16x32_bf16(ah[tn], bh[tm], acc[tn][tm], 0, 0, 0);
          acc[tn][tm] = __builtin_amdgcn_mfma_f32_16x16x32_bf16(ah[tn], bl[tm], acc[tn][tm], 0, 0, 0);
          acc[tn][tm] = __builtin_amdgcn_mfma_f32_16x16x32_bf16(al[tn], bh[tm], acc[tn][tm], 0, 0, 0);
        }
    }
#pragma unroll
    for (int tm = 0; tm < 4; ++tm) {
      float inv = invns[(size_t)b * 4096 + m0 + wm0 + tm * 16 + l16];
#pragma unroll
      for (int tn = 0; tn < 4; ++tn)
#pragma unroll
        for (int r = 0; r < 4; ++r)
          runmax[tn][r] = fmaxf(runmax[tn][r], acc[tn][tm][r] * inv);
    }
  }

#pragma unroll
  for (int off = 1; off < 16; off <<= 1)
#pragma unroll
    for (int tn = 0; tn < 4; ++tn)
#pragma unroll
      for (int r = 0; r < 4; ++r)
        runmax[tn][r] = fmaxf(runmax[tn][r], __shfl_xor(runmax[tn][r], off, 64));

  if (l16 == 0) {
#pragma unroll
    for (int tn = 0; tn < 4; ++tn)
#pragma unroll
      for (int r = 0; r < 4; ++r)
        redbuf[wave & 1][wn0 + tn * 16 + quad * 4 + r] = runmax[tn][r];
  }
  __syncthreads();
  if (tid < 128) {
    float mx = fmaxf(redbuf[0][tid], redbuf[1][tid]);
    partial[((size_t)ms * 4 + b) * 4096 + n0 + tid] = mx;
  }
}

// ---------------- final: combine 8 partials, apply invnx, mean ----------------
__global__ __launch_bounds__(256) void loss_k(const float* __restrict__ partial,
                                              const float* __restrict__ invnx,
                                              float* __restrict__ out)
{
  float sum = 0.f;
  for (int i = threadIdx.x; i < 16384; i += 256) {
    float mx = partial[i];
#pragma unroll
    for (int j = 1; j < 8; ++j) mx = fmaxf(mx, partial[j * 16384 + i]);
    sum += mx * invnx[i];
  }
  __shared__ float red[256];
  red[threadIdx.x] = sum;
  __syncthreads();
  for (int s = 128; s > 0; s >>= 1) {
    if (threadIdx.x < s) red[threadIdx.x] += red[threadIdx.x + s];
    __syncthreads();
  }
  if (threadIdx.x == 0) out[0] = 1.f - red[0] * (1.f / 16384.f);
}

extern "C" void kernel_launch(void* const* d_in, const int* in_sizes, int n_in,
                              void* d_out, int out_size, void* d_ws, size_t ws_size,
                              hipStream_t stream)
{
  const float* outputs = (const float*)d_in[0];
  const float* styles  = (const float*)d_in[1];
  const float* w[7]; const float* bs[7];
  for (int i = 0; i < 7; ++i) { w[i] = (const float*)d_in[2 + 2 * i]; bs[i] = (const float*)d_in[3 + 2 * i]; }

  // ---- workspace layout (ushort units) ----
  ushort* p = (ushort*)d_ws;
  ushort* A_h = p; p += 16777216;     // 4*256*256*64 (stage 1, per-image) == 8*128*128*128 (conv2_1 out, batch8)
  ushort* A_l = p; p += 16777216;
  ushort* B_h = p; p += 8388608;      // 8*128*128*64 (conv1_2 pooled, batch8) / 8*64*64*128 (conv2_2 pooled)
  ushort* B_l = p; p += 8388608;
  ushort* cat_h = p; p += 25165824;   // 8*4096*768
  ushort* cat_l = p; p += 25165824;
  ushort* W1p = p; p += 73728;        // 9*64*64*2
  ushort* W2p = p; p += 147456;       // 9*128*64*2
  ushort* W3p = p; p += 294912;       // 9*128*128*2
  ushort* W4p = p; p += 589824;       // 9*256*128*2
  ushort* W5p = p; p += 1179648;      // 9*256*256*2
  ushort* W6p = p; p += 1179648;
  float* nrm = (float*)p;             // 8*4096 (ssq -> invn in place)
  float* partial = nrm + 32768;       // 8*4*4096

  zero_k<<<dim3(128), 256, 0, stream>>>(nrm, 32768);

  wtrans_k<<<dim3((9*64*64   + 255)/256), 256, 0, stream>>>(w[1], W1p, 64, 64);
  wtrans_k<<<dim3((9*128*64  + 255)/256), 256, 0, stream>>>(w[2], W2p, 128, 64);
  wtrans_k<<<dim3((9*128*128 + 255)/256), 256, 0, stream>>>(w[3], W3p, 128, 128);
  wtrans_k<<<dim3((9*256*128 + 255)/256), 256, 0, stream>>>(w[4], W4p, 256, 128);
  wtrans_k<<<dim3((9*256*256 + 255)/256), 256, 0, stream>>>(w[5], W5p, 256, 256);
  wtrans_k<<<dim3((9*256*256 + 255)/256), 256, 0, stream>>>(w[6], W6p, 256, 256);

  // stage 1 per image (B=4): conv1_1 + conv1_2+pool -> batch-8 B buffer halves
  conv0_k<<<dim3(1024), 256, 0, stream>>>(outputs, w[0], bs[0], A_h, A_l);
  convmf_k<16,4,1,true,false><<<dim3(16,16,4), 256, 0, stream>>>(A_h,A_l, W1p, bs[1],
      B_h, B_l, nullptr, 256,256, 64, 64,0, 64, 64,0, 1);
  conv0_k<<<dim3(1024), 256, 0, stream>>>(styles, w[0], bs[0], A_h, A_l);
  convmf_k<16,4,1,true,false><<<dim3(16,16,4), 256, 0, stream>>>(A_h,A_l, W1p, bs[1],
      B_h + 4194304, B_l + 4194304, nullptr, 256,256, 64, 64,0, 64, 64,0, 1);

  // stage 2+ batched (B=8)
  // conv2_1: 8x128x128x64 -> 8x128x128x128 (into A)
  convmf_k<16,4,1,false,false><<<dim3(8,8,16), 256, 0, stream>>>(B_h,B_l, W2p, bs[2],
      A_h, A_l, nullptr, 128,128, 64, 64,0, 128, 128,0, 2);
  // conv2_2 + pool: -> 8x64x64x128 (into B)
  convmf_k<16,4,1,true,false><<<dim3(8,8,16), 256, 0, stream>>>(A_h,A_l, W3p, bs[3],
      B_h, B_l, nullptr, 128,128, 128, 128,0, 128, 128,0, 2);
  // conv3_1: -> cat[:, 0:256], fused ssq
  convmf_k<16,4,1,false,true><<<dim3(4,4,32), 256, 0, stream>>>(B_h,B_l, W4p, bs[4],
      cat_h, cat_l, nrm, 64,64, 128, 128,0, 256, 768,0, 4);
  // conv3_2: cat[0:256] -> cat[256:512]
  convmf_k<16,4,1,false,true><<<dim3(4,4,32), 256, 0, stream>>>(cat_h,cat_l, W5p, bs[5],
      cat_h, cat_l, nrm, 64,64, 256, 768,0, 256, 768,256, 4);
  // conv3_3: cat[256:512] -> cat[512:768]
  convmf_k<16,4,1,false,true><<<dim3(4,4,32), 256, 0, stream>>>(cat_h,cat_l, W6p, bs[6],
      cat_h, cat_l, nrm, 64,64, 256, 768,256, 256, 768,512, 4);

  finalize_k<<<dim3(128), 256, 0, stream>>>(nrm, 32768);

  simmax_k<<<dim3(32, 8, 4), 256, 0, stream>>>(cat_h, cat_l, nrm + 16384, partial);
  loss_k<<<dim3(1), 256, 0, stream>>>(partial, nrm, (float*)d_out);
}

// Round 5
// 800.180 us; speedup vs baseline: 10.1833x; 1.2015x over previous
//
#include <hip/hip_runtime.h>
#include <hip/hip_bf16.h>

__constant__ float c_mean[3] = {0.485f, 0.456f, 0.406f};
__constant__ float c_istd[3] = {1.0f/0.229f, 1.0f/0.224f, 1.0f/0.225f};

typedef __attribute__((ext_vector_type(8))) short short8;
typedef __attribute__((ext_vector_type(4))) float floatv4;
typedef unsigned short ushort;

__device__ inline float bf2f(ushort u) {
  unsigned int x = ((unsigned int)u) << 16;
  float f; __builtin_memcpy(&f, &x, 4); return f;
}
__device__ inline ushort f2bf(float f) {
  __hip_bfloat16 h = __float2bfloat16(f);
  ushort u; __builtin_memcpy(&u, &h, 2); return u;
}

// ---------------- zero ssq accumulators ----------------
__global__ __launch_bounds__(256) void zero_k(float* __restrict__ p, int n)
{
  int i = blockIdx.x * 256 + threadIdx.x;
  if (i < n) p[i] = 0.f;
}

// ---------------- weight transform: [OC][IC][3][3] fp32 -> packed MFMA B-fragments ----------------
// frag f = (kc*9 + tap)*oct16 + ot ; 1024-ushort block: [0:512) hi, [512:1024) lo
// lane L, elem j: oc = ot*16 + (L&15), ic = kc*32 + (L>>4)*8 + j
__global__ __launch_bounds__(256) void wtrans_k(const float* __restrict__ w,
                                                ushort* __restrict__ Wp,
                                                int OC, int IC)
{
  int t = blockIdx.x * 256 + threadIdx.x;
  int total = OC * IC * 9;
  if (t >= total) return;
  int oct16 = OC >> 4;
  int j = t & 7;
  int L = (t >> 3) & 63;
  int f = t >> 9;
  int ot = f % oct16;
  int r  = f / oct16;
  int tap = r % 9;
  int kc  = r / 9;
  int oc = ot * 16 + (L & 15);
  int ic = kc * 32 + ((L >> 4) << 3) + j;
  float v = w[((size_t)oc * IC + ic) * 9 + tap];
  ushort h = f2bf(v);
  Wp[(size_t)f * 1024 + L * 8 + j]       = h;
  Wp[(size_t)f * 1024 + 512 + L * 8 + j] = f2bf(v - bf2f(h));
}

// ---------------- conv1_1: IC=3 direct fp32, fused norm+bias+relu, out NHWC bf16 hi/lo ----------------
__global__ __launch_bounds__(256) void conv0_k(const float* __restrict__ img,
                                               const float* __restrict__ w,
                                               const float* __restrict__ bias,
                                               ushort* __restrict__ Yh, ushort* __restrict__ Yl)
{
  __shared__ float wl[27][64];
  __shared__ float bl[64];
  const int tid = threadIdx.x;
  for (int i = tid; i < 1728; i += 256) {
    int o = i & 63, t = i >> 6;
    wl[t][o] = w[o * 27 + t];
  }
  if (tid < 64) bl[tid] = bias[tid];
  __syncthreads();
  int px = blockIdx.x * 256 + tid;
  int b = px >> 16, rem = px & 65535;
  int y = rem >> 8, x = rem & 255;
  float iv[27];
#pragma unroll
  for (int c = 0; c < 3; ++c)
#pragma unroll
    for (int dy = 0; dy < 3; ++dy)
#pragma unroll
      for (int dx = 0; dx < 3; ++dx) {
        int gy = y - 1 + dy, gx = x - 1 + dx;
        float v = 0.f;
        if (gy >= 0 && gy < 256 && gx >= 0 && gx < 256)
          v = (img[((size_t)(b * 3 + c) * 256 + gy) * 256 + gx] - c_mean[c]) * c_istd[c];
        iv[c * 9 + dy * 3 + dx] = v;
      }
  float acc[64];
#pragma unroll
  for (int o = 0; o < 64; ++o) acc[o] = 0.f;
#pragma unroll
  for (int t = 0; t < 27; ++t) {
    float v = iv[t];
#pragma unroll
    for (int o = 0; o < 64; ++o) acc[o] = fmaf(v, wl[t][o], acc[o]);
  }
  size_t base = (size_t)px * 64;
#pragma unroll
  for (int o8 = 0; o8 < 8; ++o8) {
    short8 vh, vl;
#pragma unroll
    for (int j = 0; j < 8; ++j) {
      float v = fmaxf(acc[o8 * 8 + j] + bl[o8 * 8 + j], 0.f);
      ushort h = f2bf(v);
      vh[j] = (short)h;
      vl[j] = (short)f2bf(v - bf2f(h));
    }
    *(short8*)(Yh + base + o8 * 8) = vh;
    *(short8*)(Yl + base + o8 * 8) = vl;
  }
}

// ---------------- MFMA implicit-GEMM 3x3 conv, NHWC bf16 hi/lo, bias+relu (+pool / +ssq) ----------
// Block = 256 thr = 4 waves WPY x WPO; wave tile = 64px x 64oc; px tile = TH x 16.
template<int TH, int WPY, int WPO, bool POOL, bool SSQ>
__global__ __launch_bounds__(256) void convmf_k(
    const ushort* __restrict__ Xh, const ushort* __restrict__ Xl,
    const ushort* __restrict__ Wp,
    const float* __restrict__ bias,
    ushort* __restrict__ Yh, ushort* __restrict__ Yl,
    float* __restrict__ ssq,
    int H, int W, int IC, int in_stride, int ic_off,
    int OC, int out_stride, int oc_off, int octiles)
{
  constexpr int HR = TH + 2;
  constexpr int HALO = HR * 18;
  constexpr int OCB = WPO * 64;
  __shared__ ushort xs_h[4 * HALO * 8];
  __shared__ ushort xs_l[4 * HALO * 8];

  const int tid = threadIdx.x;
  const int wave = tid >> 6, lane = tid & 63;
  const int quad = lane >> 4, l16 = lane & 15;
  const int wy = wave / WPO, wo = wave % WPO;
  const int bb = blockIdx.z / octiles, ot = blockIdx.z % octiles;
  const int y0 = blockIdx.y * TH, x0 = blockIdx.x * 16;
  const int ocbase = ot * OCB + wo * 64;
  const int oct16 = OC >> 4;

  floatv4 acc[4][4];
#pragma unroll
  for (int tn = 0; tn < 4; ++tn)
#pragma unroll
    for (int tm = 0; tm < 4; ++tm) acc[tn][tm] = (floatv4){0.f, 0.f, 0.f, 0.f};

  for (int k0 = 0; k0 < IC; k0 += 32) {
    __syncthreads();
    for (int u = tid; u < HALO * 4; u += 256) {
      int px = u >> 2, icq = u & 3;
      int hy = px / 18, hx = px - hy * 18;
      int gy = y0 - 1 + hy, gx = x0 - 1 + hx;
      int4 vh = {0, 0, 0, 0}, vl = {0, 0, 0, 0};
      if (gy >= 0 && gy < H && gx >= 0 && gx < W) {
        size_t g = ((size_t)(bb * H + gy) * W + gx) * in_stride + ic_off + k0 + icq * 8;
        vh = *(const int4*)(Xh + g);
        vl = *(const int4*)(Xl + g);
      }
      *(int4*)&xs_h[(icq * HALO + px) * 8] = vh;
      *(int4*)&xs_l[(icq * HALO + px) * 8] = vl;
    }
    __syncthreads();

#pragma unroll
    for (int tap = 0; tap < 9; ++tap) {
      const int dy = tap / 3, dx = tap % 3;
      const size_t wg = (((size_t)(k0 >> 5) * 9 + tap) * oct16 + (ocbase >> 4)) * 1024 + (size_t)lane * 8;
      short8 bh[4], bl4[4];
#pragma unroll
      for (int tm = 0; tm < 4; ++tm) {
        bh[tm]  = *(const short8*)(Wp + wg + tm * 1024);
        bl4[tm] = *(const short8*)(Wp + wg + tm * 1024 + 512);
      }
#pragma unroll
      for (int tn = 0; tn < 4; ++tn) {
        int p = wy * 64 + tn * 16 + l16;
        int ty = p >> 4, tx = p & 15;
        int hp = (ty + dy) * 18 + tx + dx;
        short8 ah = *(const short8*)&xs_h[(quad * HALO + hp) * 8];
        short8 al = *(const short8*)&xs_l[(quad * HALO + hp) * 8];
#pragma unroll
        for (int tm = 0; tm < 4; ++tm) {
          acc[tn][tm] = __builtin_amdgcn_mfma_f32_16x16x32_bf16(ah, bh[tm],  acc[tn][tm], 0, 0, 0);
          acc[tn][tm] = __builtin_amdgcn_mfma_f32_16x16x32_bf16(ah, bl4[tm], acc[tn][tm], 0, 0, 0);
          acc[tn][tm] = __builtin_amdgcn_mfma_f32_16x16x32_bf16(al, bh[tm],  acc[tn][tm], 0, 0, 0);
        }
      }
    }
  }

  if (POOL) {
    // px p = wy*64 + tn*16 + quad*4 + r -> ty = wy*4+tn, tx = quad*4+r: 2x2 pool thread-local
    const int oH = H >> 1, oW = W >> 1;
#pragma unroll
    for (int tm = 0; tm < 4; ++tm) {
      int ocg = ocbase + tm * 16 + l16;
      float bv = bias[ocg];
#pragma unroll
      for (int tn2 = 0; tn2 < 2; ++tn2)
#pragma unroll
        for (int r2 = 0; r2 < 2; ++r2) {
          float v0 = fmaxf(acc[2 * tn2][tm][2 * r2]     + bv, 0.f);
          float v1 = fmaxf(acc[2 * tn2][tm][2 * r2 + 1] + bv, 0.f);
          float v2 = fmaxf(acc[2 * tn2 + 1][tm][2 * r2]     + bv, 0.f);
          float v3 = fmaxf(acc[2 * tn2 + 1][tm][2 * r2 + 1] + bv, 0.f);
          float v = fmaxf(fmaxf(v0, v1), fmaxf(v2, v3));
          ushort h = f2bf(v);
          ushort l = f2bf(v - bf2f(h));
          int oy = (y0 >> 1) + wy * 2 + tn2;
          int ox = (x0 >> 1) + quad * 2 + r2;
          size_t o = ((size_t)(bb * oH + oy) * oW + ox) * out_stride + oc_off + ocg;
          Yh[o] = h;
          Yl[o] = l;
        }
    }
  } else {
    float sv[4][4];
    if (SSQ) {
#pragma unroll
      for (int tn = 0; tn < 4; ++tn)
#pragma unroll
        for (int r = 0; r < 4; ++r) sv[tn][r] = 0.f;
    }
#pragma unroll
    for (int tm = 0; tm < 4; ++tm) {
      int ocg = ocbase + tm * 16 + l16;
      float bv = bias[ocg];
#pragma unroll
      for (int tn = 0; tn < 4; ++tn)
#pragma unroll
        for (int r = 0; r < 4; ++r) {
          int p = wy * 64 + tn * 16 + quad * 4 + r;
          int ty = p >> 4, tx = p & 15;
          float v = fmaxf(acc[tn][tm][r] + bv, 0.f);
          if (SSQ) sv[tn][r] = fmaf(v, v, sv[tn][r]);
          ushort h = f2bf(v);
          ushort l = f2bf(v - bf2f(h));
          size_t o = ((size_t)(bb * H + y0 + ty) * W + x0 + tx) * out_stride + oc_off + ocg;
          Yh[o] = h;
          Yl[o] = l;
        }
    }
    if (SSQ) {
#pragma unroll
      for (int tn = 0; tn < 4; ++tn)
#pragma unroll
        for (int r = 0; r < 4; ++r) {
          float s = sv[tn][r];
          s += __shfl_xor(s, 1, 64);
          s += __shfl_xor(s, 2, 64);
          s += __shfl_xor(s, 4, 64);
          s += __shfl_xor(s, 8, 64);
          if (l16 == 0) {
            int p = wy * 64 + tn * 16 + quad * 4 + r;
            int ty = p >> 4, tx = p & 15;
            atomicAdd(&ssq[(size_t)bb * 4096 + (y0 + ty) * 64 + x0 + tx], s);
          }
        }
    }
  }
}

// ---------------- finalize: ssq -> 1/(sqrt+eps) in place ----------------
__global__ __launch_bounds__(256) void finalize_k(float* __restrict__ p, int n)
{
  int i = blockIdx.x * 256 + threadIdx.x;
  if (i < n) p[i] = 1.0f / (sqrtf(p[i]) + 1e-8f);
}

// ---------------- fused sim-max GEMM, hi-only single MFMA, BK=64 ----------------
// grid (32, 8, 4); block 256 = 4 waves; block tile 128n x 128m; ms-chunk = 512 m
__global__ __launch_bounds__(256) void simmax_k(
    const ushort* __restrict__ Ch,
    const float* __restrict__ invns, float* __restrict__ partial)
{
  __shared__ ushort xh[128][72];   // 64 k + 8 pad (row stride 144 B: 16B-aligned, 4-bank shift)
  __shared__ ushort sh[128][72];
  __shared__ float redbuf[2][128];
  const int tid = threadIdx.x;
  const int lane = tid & 63, wave = tid >> 6;
  const int quad = lane >> 4, l16 = lane & 15;
  const int wn0 = (wave >> 1) * 64;
  const int wm0 = (wave & 1) * 64;
  const int n0 = blockIdx.x * 128;
  const int ms = blockIdx.y;
  const int b  = blockIdx.z;

  const int row  = tid >> 1;        // 0..127
  const int half = tid & 1;         // 32-ushort (64 B) half of the 64-k chunk

  float runmax[4][4];
#pragma unroll
  for (int tn = 0; tn < 4; ++tn)
#pragma unroll
    for (int r = 0; r < 4; ++r) runmax[tn][r] = -1e30f;

  const size_t xbase = ((size_t)b * 4096 + n0) * 768;

  for (int mc = 0; mc < 4; ++mc) {
    const int m0 = ms * 512 + mc * 128;
    const size_t sbase = ((size_t)(b + 4) * 4096 + m0) * 768;
    floatv4 acc[4][4];
#pragma unroll
    for (int tn = 0; tn < 4; ++tn)
#pragma unroll
      for (int tm = 0; tm < 4; ++tm) acc[tn][tm] = (floatv4){0.f, 0.f, 0.f, 0.f};

    for (int k0 = 0; k0 < 768; k0 += 64) {
      __syncthreads();
      const ushort* gx = Ch + xbase + (size_t)row * 768 + k0 + half * 32;
      const ushort* gs = Ch + sbase + (size_t)row * 768 + k0 + half * 32;
      ushort* lx = &xh[row][half * 32];
      ushort* ls = &sh[row][half * 32];
#pragma unroll
      for (int j = 0; j < 4; ++j) {
        *(int4*)(lx + j * 8) = *(const int4*)(gx + j * 8);
        *(int4*)(ls + j * 8) = *(const int4*)(gs + j * 8);
      }
      __syncthreads();
#pragma unroll
      for (int ks = 0; ks < 2; ++ks) {
        short8 ah[4], bh[4];
#pragma unroll
        for (int t = 0; t < 4; ++t) {
          ah[t] = *(const short8*)&xh[wn0 + t * 16 + l16][ks * 32 + quad * 8];
          bh[t] = *(const short8*)&sh[wm0 + t * 16 + l16][ks * 32 + quad * 8];
        }
#pragma unroll
        for (int tn = 0; tn < 4; ++tn)
#pragma unroll
          for (int tm = 0; tm < 4; ++tm)
            acc[tn][tm] = __builtin_amdgcn_mfma_f32_16x16x32_bf16(ah[tn], bh[tm], acc[tn][tm], 0, 0, 0);
      }
    }
#pragma unroll
    for (int tm = 0; tm < 4; ++tm) {
      float inv = invns[(size_t)b * 4096 + m0 + wm0 + tm * 16 + l16];
#pragma unroll
      for (int tn = 0; tn < 4; ++tn)
#pragma unroll
        for (int r = 0; r < 4; ++r)
          runmax[tn][r] = fmaxf(runmax[tn][r], acc[tn][tm][r] * inv);
    }
  }

#pragma unroll
  for (int off = 1; off < 16; off <<= 1)
#pragma unroll
    for (int tn = 0; tn < 4; ++tn)
#pragma unroll
      for (int r = 0; r < 4; ++r)
        runmax[tn][r] = fmaxf(runmax[tn][r], __shfl_xor(runmax[tn][r], off, 64));

  if (l16 == 0) {
#pragma unroll
    for (int tn = 0; tn < 4; ++tn)
#pragma unroll
      for (int r = 0; r < 4; ++r)
        redbuf[wave & 1][wn0 + tn * 16 + quad * 4 + r] = runmax[tn][r];
  }
  __syncthreads();
  if (tid < 128) {
    float mx = fmaxf(redbuf[0][tid], redbuf[1][tid]);
    partial[((size_t)ms * 4 + b) * 4096 + n0 + tid] = mx;
  }
}

// ---------------- final: combine 8 partials, apply invnx, mean ----------------
__global__ __launch_bounds__(256) void loss_k(const float* __restrict__ partial,
                                              const float* __restrict__ invnx,
                                              float* __restrict__ out)
{
  float sum = 0.f;
  for (int i = threadIdx.x; i < 16384; i += 256) {
    float mx = partial[i];
#pragma unroll
    for (int j = 1; j < 8; ++j) mx = fmaxf(mx, partial[j * 16384 + i]);
    sum += mx * invnx[i];
  }
  __shared__ float red[256];
  red[threadIdx.x] = sum;
  __syncthreads();
  for (int s = 128; s > 0; s >>= 1) {
    if (threadIdx.x < s) red[threadIdx.x] += red[threadIdx.x + s];
    __syncthreads();
  }
  if (threadIdx.x == 0) out[0] = 1.f - red[0] * (1.f / 16384.f);
}

extern "C" void kernel_launch(void* const* d_in, const int* in_sizes, int n_in,
                              void* d_out, int out_size, void* d_ws, size_t ws_size,
                              hipStream_t stream)
{
  const float* outputs = (const float*)d_in[0];
  const float* styles  = (const float*)d_in[1];
  const float* w[7]; const float* bs[7];
  for (int i = 0; i < 7; ++i) { w[i] = (const float*)d_in[2 + 2 * i]; bs[i] = (const float*)d_in[3 + 2 * i]; }

  // ---- workspace layout (ushort units) ----
  ushort* p = (ushort*)d_ws;
  ushort* A_h = p; p += 16777216;     // 4*256*256*64 (stage 1) == 8*128*128*128 (conv2_1 out)
  ushort* A_l = p; p += 16777216;
  ushort* B_h = p; p += 8388608;      // 8*128*128*64 / 8*64*64*128
  ushort* B_l = p; p += 8388608;
  ushort* cat_h = p; p += 25165824;   // 8*4096*768
  ushort* cat_l = p; p += 25165824;
  ushort* W1p = p; p += 73728;
  ushort* W2p = p; p += 147456;
  ushort* W3p = p; p += 294912;
  ushort* W4p = p; p += 589824;
  ushort* W5p = p; p += 1179648;
  ushort* W6p = p; p += 1179648;
  float* nrm = (float*)p;             // 8*4096 (ssq -> invn in place)
  float* partial = nrm + 32768;       // 8*4*4096

  zero_k<<<dim3(128), 256, 0, stream>>>(nrm, 32768);

  wtrans_k<<<dim3((9*64*64   + 255)/256), 256, 0, stream>>>(w[1], W1p, 64, 64);
  wtrans_k<<<dim3((9*128*64  + 255)/256), 256, 0, stream>>>(w[2], W2p, 128, 64);
  wtrans_k<<<dim3((9*128*128 + 255)/256), 256, 0, stream>>>(w[3], W3p, 128, 128);
  wtrans_k<<<dim3((9*256*128 + 255)/256), 256, 0, stream>>>(w[4], W4p, 256, 128);
  wtrans_k<<<dim3((9*256*256 + 255)/256), 256, 0, stream>>>(w[5], W5p, 256, 256);
  wtrans_k<<<dim3((9*256*256 + 255)/256), 256, 0, stream>>>(w[6], W6p, 256, 256);

  // stage 1 per image (B=4): conv1_1 + conv1_2+pool -> batch-8 B buffer halves
  conv0_k<<<dim3(1024), 256, 0, stream>>>(outputs, w[0], bs[0], A_h, A_l);
  convmf_k<16,4,1,true,false><<<dim3(16,16,4), 256, 0, stream>>>(A_h,A_l, W1p, bs[1],
      B_h, B_l, nullptr, 256,256, 64, 64,0, 64, 64,0, 1);
  conv0_k<<<dim3(1024), 256, 0, stream>>>(styles, w[0], bs[0], A_h, A_l);
  convmf_k<16,4,1,true,false><<<dim3(16,16,4), 256, 0, stream>>>(A_h,A_l, W1p, bs[1],
      B_h + 4194304, B_l + 4194304, nullptr, 256,256, 64, 64,0, 64, 64,0, 1);

  // stage 2+ batched (B=8)
  convmf_k<16,4,1,false,false><<<dim3(8,8,16), 256, 0, stream>>>(B_h,B_l, W2p, bs[2],
      A_h, A_l, nullptr, 128,128, 64, 64,0, 128, 128,0, 2);
  convmf_k<16,4,1,true,false><<<dim3(8,8,16), 256, 0, stream>>>(A_h,A_l, W3p, bs[3],
      B_h, B_l, nullptr, 128,128, 128, 128,0, 128, 128,0, 2);
  convmf_k<16,4,1,false,true><<<dim3(4,4,32), 256, 0, stream>>>(B_h,B_l, W4p, bs[4],
      cat_h, cat_l, nrm, 64,64, 128, 128,0, 256, 768,0, 4);
  convmf_k<16,4,1,false,true><<<dim3(4,4,32), 256, 0, stream>>>(cat_h,cat_l, W5p, bs[5],
      cat_h, cat_l, nrm, 64,64, 256, 768,0, 256, 768,256, 4);
  convmf_k<16,4,1,false,true><<<dim3(4,4,32), 256, 0, stream>>>(cat_h,cat_l, W6p, bs[6],
      cat_h, cat_l, nrm, 64,64, 256, 768,256, 256, 768,512, 4);

  finalize_k<<<dim3(128), 256, 0, stream>>>(nrm, 32768);

  simmax_k<<<dim3(32, 8, 4), 256, 0, stream>>>(cat_h, nrm + 16384, partial);
  loss_k<<<dim3(1), 256, 0, stream>>>(partial, nrm, (float*)d_out);
}

// Round 6
// 658.834 us; speedup vs baseline: 12.3680x; 1.2145x over previous
//
#include <hip/hip_runtime.h>
#include <hip/hip_bf16.h>

__constant__ float c_mean[3] = {0.485f, 0.456f, 0.406f};
__constant__ float c_istd[3] = {1.0f/0.229f, 1.0f/0.224f, 1.0f/0.225f};

typedef __attribute__((ext_vector_type(8))) short short8;
typedef __attribute__((ext_vector_type(4))) float floatv4;
typedef unsigned short ushort;

__device__ inline float bf2f(ushort u) {
  unsigned int x = ((unsigned int)u) << 16;
  float f; __builtin_memcpy(&f, &x, 4); return f;
}
__device__ inline ushort f2bf(float f) {
  __hip_bfloat16 h = __float2bfloat16(f);
  ushort u; __builtin_memcpy(&u, &h, 2); return u;
}

// ---------------- zero ssq accumulators ----------------
__global__ __launch_bounds__(256) void zero_k(float* __restrict__ p, int n)
{
  int i = blockIdx.x * 256 + threadIdx.x;
  if (i < n) p[i] = 0.f;
}

// ---------------- weight transform: [OC][IC][3][3] fp32 -> packed MFMA B-fragments ----------------
// frag f = (kc*9 + tap)*oct16 + ot ; 1024-ushort block: [0:512) hi, [512:1024) lo
// lane L, elem j: oc = ot*16 + (L&15), ic = kc*32 + (L>>4)*8 + j
__global__ __launch_bounds__(256) void wtrans_k(const float* __restrict__ w,
                                                ushort* __restrict__ Wp,
                                                int OC, int IC)
{
  int t = blockIdx.x * 256 + threadIdx.x;
  int total = OC * IC * 9;
  if (t >= total) return;
  int oct16 = OC >> 4;
  int j = t & 7;
  int L = (t >> 3) & 63;
  int f = t >> 9;
  int ot = f % oct16;
  int r  = f / oct16;
  int tap = r % 9;
  int kc  = r / 9;
  int oc = ot * 16 + (L & 15);
  int ic = kc * 32 + ((L >> 4) << 3) + j;
  float v = w[((size_t)oc * IC + ic) * 9 + tap];
  ushort h = f2bf(v);
  Wp[(size_t)f * 1024 + L * 8 + j]       = h;
  Wp[(size_t)f * 1024 + 512 + L * 8 + j] = f2bf(v - bf2f(h));
}

// ---------------- conv1_1: IC=3 direct fp32, batch 8 (outputs||styles), out NHWC bf16 ----------------
__global__ __launch_bounds__(256) void conv0_k(const float* __restrict__ imgA,
                                               const float* __restrict__ imgB,
                                               const float* __restrict__ w,
                                               const float* __restrict__ bias,
                                               ushort* __restrict__ Yh)
{
  __shared__ float wl[27][64];
  __shared__ float bl[64];
  const int tid = threadIdx.x;
  for (int i = tid; i < 1728; i += 256) {
    int o = i & 63, t = i >> 6;
    wl[t][o] = w[o * 27 + t];
  }
  if (tid < 64) bl[tid] = bias[tid];
  __syncthreads();
  int px = blockIdx.x * 256 + tid;
  int b = px >> 16, rem = px & 65535;
  int y = rem >> 8, x = rem & 255;
  const float* img = (b < 4) ? (imgA + (size_t)b * 3 * 65536)
                             : (imgB + (size_t)(b - 4) * 3 * 65536);
  float iv[27];
#pragma unroll
  for (int c = 0; c < 3; ++c)
#pragma unroll
    for (int dy = 0; dy < 3; ++dy)
#pragma unroll
      for (int dx = 0; dx < 3; ++dx) {
        int gy = y - 1 + dy, gx = x - 1 + dx;
        float v = 0.f;
        if (gy >= 0 && gy < 256 && gx >= 0 && gx < 256)
          v = (img[(size_t)c * 65536 + gy * 256 + gx] - c_mean[c]) * c_istd[c];
        iv[c * 9 + dy * 3 + dx] = v;
      }
  float acc[64];
#pragma unroll
  for (int o = 0; o < 64; ++o) acc[o] = 0.f;
#pragma unroll
  for (int t = 0; t < 27; ++t) {
    float v = iv[t];
#pragma unroll
    for (int o = 0; o < 64; ++o) acc[o] = fmaf(v, wl[t][o], acc[o]);
  }
  size_t base = (size_t)px * 64;
#pragma unroll
  for (int o8 = 0; o8 < 8; ++o8) {
    short8 vh;
#pragma unroll
    for (int j = 0; j < 8; ++j)
      vh[j] = (short)f2bf(fmaxf(acc[o8 * 8 + j] + bl[o8 * 8 + j], 0.f));
    *(short8*)(Yh + base + o8 * 8) = vh;
  }
}

// ---------------- MFMA implicit-GEMM 3x3 conv, NHWC bf16 act, hi/lo weights (2 MFMA/tap) ----------
// Block = 256 thr = 4 waves WPY x WPO; wave tile = 64px x 64oc; px tile = TH x 16.
template<int TH, int WPY, int WPO, bool POOL, bool SSQ>
__global__ __launch_bounds__(256) void convmf_k(
    const ushort* __restrict__ Xh,
    const ushort* __restrict__ Wp,
    const float* __restrict__ bias,
    ushort* __restrict__ Yh,
    float* __restrict__ ssq,
    int H, int W, int IC, int in_stride, int ic_off,
    int OC, int out_stride, int oc_off, int octiles)
{
  constexpr int HR = TH + 2;
  constexpr int HALO = HR * 18;
  constexpr int OCB = WPO * 64;
  __shared__ ushort xs_h[4 * HALO * 8];

  const int tid = threadIdx.x;
  const int wave = tid >> 6, lane = tid & 63;
  const int quad = lane >> 4, l16 = lane & 15;
  const int wy = wave / WPO, wo = wave % WPO;
  const int bb = blockIdx.z / octiles, ot = blockIdx.z % octiles;
  const int y0 = blockIdx.y * TH, x0 = blockIdx.x * 16;
  const int ocbase = ot * OCB + wo * 64;
  const int oct16 = OC >> 4;

  floatv4 acc[4][4];
#pragma unroll
  for (int tn = 0; tn < 4; ++tn)
#pragma unroll
    for (int tm = 0; tm < 4; ++tm) acc[tn][tm] = (floatv4){0.f, 0.f, 0.f, 0.f};

  for (int k0 = 0; k0 < IC; k0 += 32) {
    __syncthreads();
    for (int u = tid; u < HALO * 4; u += 256) {
      int px = u >> 2, icq = u & 3;
      int hy = px / 18, hx = px - hy * 18;
      int gy = y0 - 1 + hy, gx = x0 - 1 + hx;
      int4 vh = {0, 0, 0, 0};
      if (gy >= 0 && gy < H && gx >= 0 && gx < W) {
        size_t g = ((size_t)(bb * H + gy) * W + gx) * in_stride + ic_off + k0 + icq * 8;
        vh = *(const int4*)(Xh + g);
      }
      *(int4*)&xs_h[(icq * HALO + px) * 8] = vh;
    }
    __syncthreads();

#pragma unroll
    for (int tap = 0; tap < 9; ++tap) {
      const int dy = tap / 3, dx = tap % 3;
      const size_t wg = (((size_t)(k0 >> 5) * 9 + tap) * oct16 + (ocbase >> 4)) * 1024 + (size_t)lane * 8;
      short8 bh[4], bl4[4];
#pragma unroll
      for (int tm = 0; tm < 4; ++tm) {
        bh[tm]  = *(const short8*)(Wp + wg + tm * 1024);
        bl4[tm] = *(const short8*)(Wp + wg + tm * 1024 + 512);
      }
#pragma unroll
      for (int tn = 0; tn < 4; ++tn) {
        int p = wy * 64 + tn * 16 + l16;
        int ty = p >> 4, tx = p & 15;
        int hp = (ty + dy) * 18 + tx + dx;
        short8 ah = *(const short8*)&xs_h[(quad * HALO + hp) * 8];
#pragma unroll
        for (int tm = 0; tm < 4; ++tm) {
          acc[tn][tm] = __builtin_amdgcn_mfma_f32_16x16x32_bf16(ah, bh[tm],  acc[tn][tm], 0, 0, 0);
          acc[tn][tm] = __builtin_amdgcn_mfma_f32_16x16x32_bf16(ah, bl4[tm], acc[tn][tm], 0, 0, 0);
        }
      }
    }
  }

  if (POOL) {
    // px p = wy*64 + tn*16 + quad*4 + r -> ty = wy*4+tn, tx = quad*4+r: 2x2 pool thread-local
    const int oH = H >> 1, oW = W >> 1;
#pragma unroll
    for (int tm = 0; tm < 4; ++tm) {
      int ocg = ocbase + tm * 16 + l16;
      float bv = bias[ocg];
#pragma unroll
      for (int tn2 = 0; tn2 < 2; ++tn2)
#pragma unroll
        for (int r2 = 0; r2 < 2; ++r2) {
          float v0 = fmaxf(acc[2 * tn2][tm][2 * r2]     + bv, 0.f);
          float v1 = fmaxf(acc[2 * tn2][tm][2 * r2 + 1] + bv, 0.f);
          float v2 = fmaxf(acc[2 * tn2 + 1][tm][2 * r2]     + bv, 0.f);
          float v3 = fmaxf(acc[2 * tn2 + 1][tm][2 * r2 + 1] + bv, 0.f);
          float v = fmaxf(fmaxf(v0, v1), fmaxf(v2, v3));
          int oy = (y0 >> 1) + wy * 2 + tn2;
          int ox = (x0 >> 1) + quad * 2 + r2;
          Yh[((size_t)(bb * oH + oy) * oW + ox) * out_stride + oc_off + ocg] = f2bf(v);
        }
    }
  } else {
    float sv[4][4];
    if (SSQ) {
#pragma unroll
      for (int tn = 0; tn < 4; ++tn)
#pragma unroll
        for (int r = 0; r < 4; ++r) sv[tn][r] = 0.f;
    }
#pragma unroll
    for (int tm = 0; tm < 4; ++tm) {
      int ocg = ocbase + tm * 16 + l16;
      float bv = bias[ocg];
#pragma unroll
      for (int tn = 0; tn < 4; ++tn)
#pragma unroll
        for (int r = 0; r < 4; ++r) {
          int p = wy * 64 + tn * 16 + quad * 4 + r;
          int ty = p >> 4, tx = p & 15;
          float v = fmaxf(acc[tn][tm][r] + bv, 0.f);
          ushort h = f2bf(v);
          if (SSQ) { float vr = bf2f(h); sv[tn][r] = fmaf(vr, vr, sv[tn][r]); }
          Yh[((size_t)(bb * H + y0 + ty) * W + x0 + tx) * out_stride + oc_off + ocg] = h;
        }
    }
    if (SSQ) {
#pragma unroll
      for (int tn = 0; tn < 4; ++tn)
#pragma unroll
        for (int r = 0; r < 4; ++r) {
          float s = sv[tn][r];
          s += __shfl_xor(s, 1, 64);
          s += __shfl_xor(s, 2, 64);
          s += __shfl_xor(s, 4, 64);
          s += __shfl_xor(s, 8, 64);
          if (l16 == 0) {
            int p = wy * 64 + tn * 16 + quad * 4 + r;
            int ty = p >> 4, tx = p & 15;
            atomicAdd(&ssq[(size_t)bb * 4096 + (y0 + ty) * 64 + x0 + tx], s);
          }
        }
    }
  }
}

// ---------------- finalize: ssq -> 1/(sqrt+eps) in place ----------------
__global__ __launch_bounds__(256) void finalize_k(float* __restrict__ p, int n)
{
  int i = blockIdx.x * 256 + threadIdx.x;
  if (i < n) p[i] = 1.0f / (sqrtf(p[i]) + 1e-8f);
}

// ---------------- fused sim-max GEMM, hi-only single MFMA, BK=64 ----------------
// grid (32, 8, 4); block 256 = 4 waves; block tile 128n x 128m; ms-chunk = 512 m
__global__ __launch_bounds__(256) void simmax_k(
    const ushort* __restrict__ Ch,
    const float* __restrict__ invns, float* __restrict__ partial)
{
  __shared__ ushort xh[128][72];   // 64 k + 8 pad
  __shared__ ushort sh[128][72];
  __shared__ float redbuf[2][128];
  const int tid = threadIdx.x;
  const int lane = tid & 63, wave = tid >> 6;
  const int quad = lane >> 4, l16 = lane & 15;
  const int wn0 = (wave >> 1) * 64;
  const int wm0 = (wave & 1) * 64;
  const int n0 = blockIdx.x * 128;
  const int ms = blockIdx.y;
  const int b  = blockIdx.z;

  const int row  = tid >> 1;        // 0..127
  const int half = tid & 1;

  float runmax[4][4];
#pragma unroll
  for (int tn = 0; tn < 4; ++tn)
#pragma unroll
    for (int r = 0; r < 4; ++r) runmax[tn][r] = -1e30f;

  const size_t xbase = ((size_t)b * 4096 + n0) * 768;

  for (int mc = 0; mc < 4; ++mc) {
    const int m0 = ms * 512 + mc * 128;
    const size_t sbase = ((size_t)(b + 4) * 4096 + m0) * 768;
    floatv4 acc[4][4];
#pragma unroll
    for (int tn = 0; tn < 4; ++tn)
#pragma unroll
      for (int tm = 0; tm < 4; ++tm) acc[tn][tm] = (floatv4){0.f, 0.f, 0.f, 0.f};

    for (int k0 = 0; k0 < 768; k0 += 64) {
      __syncthreads();
      const ushort* gx = Ch + xbase + (size_t)row * 768 + k0 + half * 32;
      const ushort* gs = Ch + sbase + (size_t)row * 768 + k0 + half * 32;
      ushort* lx = &xh[row][half * 32];
      ushort* ls = &sh[row][half * 32];
#pragma unroll
      for (int j = 0; j < 4; ++j) {
        *(int4*)(lx + j * 8) = *(const int4*)(gx + j * 8);
        *(int4*)(ls + j * 8) = *(const int4*)(gs + j * 8);
      }
      __syncthreads();
#pragma unroll
      for (int ks = 0; ks < 2; ++ks) {
        short8 ah[4], bh[4];
#pragma unroll
        for (int t = 0; t < 4; ++t) {
          ah[t] = *(const short8*)&xh[wn0 + t * 16 + l16][ks * 32 + quad * 8];
          bh[t] = *(const short8*)&sh[wm0 + t * 16 + l16][ks * 32 + quad * 8];
        }
#pragma unroll
        for (int tn = 0; tn < 4; ++tn)
#pragma unroll
          for (int tm = 0; tm < 4; ++tm)
            acc[tn][tm] = __builtin_amdgcn_mfma_f32_16x16x32_bf16(ah[tn], bh[tm], acc[tn][tm], 0, 0, 0);
      }
    }
#pragma unroll
    for (int tm = 0; tm < 4; ++tm) {
      float inv = invns[(size_t)b * 4096 + m0 + wm0 + tm * 16 + l16];
#pragma unroll
      for (int tn = 0; tn < 4; ++tn)
#pragma unroll
        for (int r = 0; r < 4; ++r)
          runmax[tn][r] = fmaxf(runmax[tn][r], acc[tn][tm][r] * inv);
    }
  }

#pragma unroll
  for (int off = 1; off < 16; off <<= 1)
#pragma unroll
    for (int tn = 0; tn < 4; ++tn)
#pragma unroll
      for (int r = 0; r < 4; ++r)
        runmax[tn][r] = fmaxf(runmax[tn][r], __shfl_xor(runmax[tn][r], off, 64));

  if (l16 == 0) {
#pragma unroll
    for (int tn = 0; tn < 4; ++tn)
#pragma unroll
      for (int r = 0; r < 4; ++r)
        redbuf[wave & 1][wn0 + tn * 16 + quad * 4 + r] = runmax[tn][r];
  }
  __syncthreads();
  if (tid < 128) {
    float mx = fmaxf(redbuf[0][tid], redbuf[1][tid]);
    partial[((size_t)ms * 4 + b) * 4096 + n0 + tid] = mx;
  }
}

// ---------------- final: combine 8 partials, apply invnx, mean ----------------
__global__ __launch_bounds__(256) void loss_k(const float* __restrict__ partial,
                                              const float* __restrict__ invnx,
                                              float* __restrict__ out)
{
  float sum = 0.f;
  for (int i = threadIdx.x; i < 16384; i += 256) {
    float mx = partial[i];
#pragma unroll
    for (int j = 1; j < 8; ++j) mx = fmaxf(mx, partial[j * 16384 + i]);
    sum += mx * invnx[i];
  }
  __shared__ float red[256];
  red[threadIdx.x] = sum;
  __syncthreads();
  for (int s = 128; s > 0; s >>= 1) {
    if (threadIdx.x < s) red[threadIdx.x] += red[threadIdx.x + s];
    __syncthreads();
  }
  if (threadIdx.x == 0) out[0] = 1.f - red[0] * (1.f / 16384.f);
}

extern "C" void kernel_launch(void* const* d_in, const int* in_sizes, int n_in,
                              void* d_out, int out_size, void* d_ws, size_t ws_size,
                              hipStream_t stream)
{
  const float* outputs = (const float*)d_in[0];
  const float* styles  = (const float*)d_in[1];
  const float* w[7]; const float* bs[7];
  for (int i = 0; i < 7; ++i) { w[i] = (const float*)d_in[2 + 2 * i]; bs[i] = (const float*)d_in[3 + 2 * i]; }

  // ---- workspace layout (ushort units) ----
  ushort* p = (ushort*)d_ws;
  ushort* A_h = p; p += 33554432;     // 8*256*256*64 (conv1_1 out) == 8*128*128*128 (conv2_1 out)
  ushort* B_h = p; p += 8388608;      // 8*128*128*64 (conv1_2 pooled) == 8*64*64*128 (conv2_2 pooled)
  ushort* cat_h = p; p += 25165824;   // 8*4096*768
  ushort* W1p = p; p += 73728;
  ushort* W2p = p; p += 147456;
  ushort* W3p = p; p += 294912;
  ushort* W4p = p; p += 589824;
  ushort* W5p = p; p += 1179648;
  ushort* W6p = p; p += 1179648;
  float* nrm = (float*)p;             // 8*4096 (ssq -> invn in place)
  float* partial = nrm + 32768;       // 8*4*4096

  zero_k<<<dim3(128), 256, 0, stream>>>(nrm, 32768);

  wtrans_k<<<dim3((9*64*64   + 255)/256), 256, 0, stream>>>(w[1], W1p, 64, 64);
  wtrans_k<<<dim3((9*128*64  + 255)/256), 256, 0, stream>>>(w[2], W2p, 128, 64);
  wtrans_k<<<dim3((9*128*128 + 255)/256), 256, 0, stream>>>(w[3], W3p, 128, 128);
  wtrans_k<<<dim3((9*256*128 + 255)/256), 256, 0, stream>>>(w[4], W4p, 256, 128);
  wtrans_k<<<dim3((9*256*256 + 255)/256), 256, 0, stream>>>(w[5], W5p, 256, 256);
  wtrans_k<<<dim3((9*256*256 + 255)/256), 256, 0, stream>>>(w[6], W6p, 256, 256);

  // conv1_1 batch 8 (outputs || styles)
  conv0_k<<<dim3(2048), 256, 0, stream>>>(outputs, styles, w[0], bs[0], A_h);
  // conv1_2 + pool: 8x256x256x64 -> 8x128x128x64
  convmf_k<16,4,1,true,false><<<dim3(16,16,8), 256, 0, stream>>>(A_h, W1p, bs[1],
      B_h, nullptr, 256,256, 64, 64,0, 64, 64,0, 1);
  // conv2_1: -> 8x128x128x128
  convmf_k<16,4,1,false,false><<<dim3(8,8,16), 256, 0, stream>>>(B_h, W2p, bs[2],
      A_h, nullptr, 128,128, 64, 64,0, 128, 128,0, 2);
  // conv2_2 + pool: -> 8x64x64x128
  convmf_k<16,4,1,true,false><<<dim3(8,8,16), 256, 0, stream>>>(A_h, W3p, bs[3],
      B_h, nullptr, 128,128, 128, 128,0, 128, 128,0, 2);
  // conv3_1: -> cat[:, 0:256], fused ssq
  convmf_k<16,4,1,false,true><<<dim3(4,4,32), 256, 0, stream>>>(B_h, W4p, bs[4],
      cat_h, nrm, 64,64, 128, 128,0, 256, 768,0, 4);
  // conv3_2: cat[0:256] -> cat[256:512]
  convmf_k<16,4,1,false,true><<<dim3(4,4,32), 256, 0, stream>>>(cat_h, W5p, bs[5],
      cat_h, nrm, 64,64, 256, 768,0, 256, 768,256, 4);
  // conv3_3: cat[256:512] -> cat[512:768]
  convmf_k<16,4,1,false,true><<<dim3(4,4,32), 256, 0, stream>>>(cat_h, W6p, bs[6],
      cat_h, nrm, 64,64, 256, 768,256, 256, 768,512, 4);

  finalize_k<<<dim3(128), 256, 0, stream>>>(nrm, 32768);

  simmax_k<<<dim3(32, 8, 4), 256, 0, stream>>>(cat_h, nrm + 16384, partial);
  loss_k<<<dim3(1), 256, 0, stream>>>(partial, nrm, (float*)d_out);
}